// Round 1
// 835.249 us; speedup vs baseline: 1.7311x; 1.7311x over previous
//
#include <hip/hip_runtime.h>

#define NNODE 4096
#define NPB   1024

__device__ __forceinline__ float siluf(float x){ return x / (1.0f + expf(-x)); }

// ---------------- LDS layout (floats), 7680 floats = 30720 B ----------------
// Region A: 0..3072    CRD(P0) | RB(rbf->P7) | RED(P10,P13) | HF(P11-12)
// Region B: 3072..5184 HD(P7-8) | AG(agg->P10)
// Region C: 5184..7296 QS/QD/LG/SX(P1-P5) | EH(P8-agg) | HL(P10-11)
// Region D: 7296..7504 AT, KI, KD, SS, LEN, VL (long-lived smalls)
#define O_CRD  0
#define O_RB   0
#define O_RED  0
#define O_HF   0
#define O_HD   3072
#define O_AG   3072
#define O_EH   5184
#define O_HL   5184
#define O_QS   5184  /* 16 x 64 */
#define O_QD   6208  /* 64 */
#define O_LG   6272  /* 128 */
#define O_SX   6400  /* 24 */
#define O_AT   7296  /* 128 */
#define O_KI   7424  /* 16 ints */
#define O_KD   7440  /* 16 */
#define O_SS   7456  /* 16 */
#define O_LEN  7472  /* 16 */
#define O_VL   7488  /* 16 */

// ---------- K0: film = mish(cond) @ Wfilm + bfilm -> d_ws (4 x 2304 f32) ----------
__global__ __launch_bounds__(256) void k_film(const float* __restrict__ cond,
                                              const float* __restrict__ Wfilm,
                                              const float* __restrict__ bfilm,
                                              float* __restrict__ filmG){
  __shared__ float mL[256];
  int b = blockIdx.y;
  int t = threadIdx.x;
  int j = blockIdx.x*256 + t;
  float x = cond[b*256 + t];
  float sp = fmaxf(x, 0.f) + log1pf(expf(-fabsf(x)));
  mL[t] = x * tanhf(sp);
  __syncthreads();
  if(j >= 2304) return;
  float acc = bfilm[j];
  for(int i=0;i<256;i++) acc += mL[i] * Wfilm[i*2304 + j];
  filmG[b*2304 + j] = acc;
}

// ---------- K1: per-node precompute ----------
// Z  = emb @ Wv          (N x 9 x 128)   -- rotations cancel, so this is edge-invariant
// Qs = emb[:,0] @ Wsrc   (N x 64)
// Qd = emb[:,0] @ Wdst   (N x 64)
__global__ __launch_bounds__(128) void k_pre(const float* __restrict__ emb,
                                             const float* __restrict__ Wv,
                                             const float* __restrict__ Wsrc,
                                             const float* __restrict__ Wdst,
                                             float* __restrict__ ZG,
                                             float* __restrict__ QsG,
                                             float* __restrict__ QdG){
  __shared__ __align__(16) float Es[1152];
  const int n = blockIdx.x;
  const int t = threadIdx.x;
  {
    const float4* src = (const float4*)(emb + (size_t)n*1152);
    float4* dst = (float4*)Es;
    for(int idx=t; idx<288; idx+=128) dst[idx] = src[idx];
  }
  __syncthreads();
  float z[9];
  #pragma unroll
  for(int l=0;l<9;l++) z[l]=0.f;
  for(int c4=0;c4<32;c4++){
    float w0 = Wv[(c4*4+0)*128 + t];
    float w1 = Wv[(c4*4+1)*128 + t];
    float w2 = Wv[(c4*4+2)*128 + t];
    float w3 = Wv[(c4*4+3)*128 + t];
    #pragma unroll
    for(int l=0;l<9;l++){
      float4 x4 = *(const float4*)&Es[l*128 + c4*4];
      z[l] += x4.x*w0 + x4.y*w1 + x4.z*w2 + x4.w*w3;
    }
  }
  #pragma unroll
  for(int l=0;l<9;l++) ZG[(size_t)n*1152 + l*128 + t] = z[l];
  {
    const float* W = (t < 64) ? Wsrc : Wdst;
    const int col = t & 63;
    float q = 0.f;
    for(int c=0;c<128;c++) q += Es[c] * W[c*64 + col];
    if(t < 64) QsG[n*64 + col] = q;
    else       QdG[n*64 + col] = q;
  }
}

// ---------- K2: main per-node kernel ----------
__global__ __launch_bounds__(128, 4) void k_node(
    const float* __restrict__ coord,
    const float* __restrict__ emb,
    const float* __restrict__ We1, const float* __restrict__ be1,
    const float* __restrict__ We2, const float* __restrict__ be2,
    const float* __restrict__ wa,
    const float* __restrict__ Wo,
    const float* __restrict__ g1, const float* __restrict__ g2,
    const float* __restrict__ Wg, const float* __restrict__ Wf1,
    const float* __restrict__ Wf2,
    const float* __restrict__ Qs, const float* __restrict__ Qd,
    const float* __restrict__ Z,
    const float* __restrict__ filmG,
    float* __restrict__ out){
  __shared__ __align__(16) float S[7680];
  int* Si = (int*)S;
  const int n = blockIdx.x;
  const int t = threadIdx.x;
  const int base = n & ~(NPB - 1);
  const int self = n - base;

  // ---- P0: stage coords; wave 0 does the full KNN (no barriers inside) ----
  for(int idx = t; idx < 3072; idx += 128) S[O_CRD + idx] = coord[base*3 + idx];
  __syncthreads();
  const float cx = S[O_CRD + self*3+0];
  const float cy = S[O_CRD + self*3+1];
  const float cz = S[O_CRD + self*3+2];
  if(t < 64){
    float d2a[16]; int ida[16];
    for(int q=0;q<16;q++){
      int j = t + q*64;
      float dx = __fsub_rn(S[O_CRD + j*3+0], cx);
      float dy = __fsub_rn(S[O_CRD + j*3+1], cy);
      float dz = __fsub_rn(S[O_CRD + j*3+2], cz);
      float d2 = __fadd_rn(__fadd_rn(__fmul_rn(dx,dx), __fmul_rn(dy,dy)), __fmul_rn(dz,dz));
      if(j == self) d2 = 3e38f;
      d2a[q] = d2; ida[q] = j;
    }
    for(int r=0;r<16;r++){
      float bd = d2a[0]; int bi = ida[0];
      for(int q=1;q<16;q++){
        bool bet = (d2a[q] < bd) || (d2a[q] == bd && ida[q] < bi);
        if(bet){ bd = d2a[q]; bi = ida[q]; }
      }
      for(int s=1;s<64;s<<=1){
        float od = __shfl_xor(bd, s, 64);
        int   oi = __shfl_xor(bi, s, 64);
        bool bet = (od < bd) || (od == bd && oi < bi);
        if(bet){ bd = od; bi = oi; }
      }
      if(t == 0){ Si[O_KI + r] = bi; S[O_KD + r] = bd; }
      for(int q=0;q<16;q++) if(ida[q] == bi) d2a[q] = 3e38f;
    }
  }
  __syncthreads();

  // ---- P1: edge len/valid (t<16) + stage Qs[src] rows + Qd[n] ----
  if(t < 16){
    float len = __fsqrt_rn(S[O_KD + t]);
    S[O_LEN + t] = len;
    S[O_VL + t]  = (len <= 3.0f) ? 1.0f : 0.0f;
  }
  for(int idx = t; idx < 1024; idx += 128){
    int e = idx >> 6, ha = idx & 63;
    int src = base + Si[O_KI + e];
    S[O_QS + idx] = Qs[src*64 + ha];
  }
  if(t < 64) S[O_QD + t] = Qd[n*64 + t];
  __syncthreads();

  // ---- P2: logits (all threads: e=t>>3, h=t&7) + rbf ----
  {
    int e = t >> 3, h = t & 7;
    float s = 0.f;
    #pragma unroll
    for(int a=0;a<8;a++){
      float q = S[O_QD + h*8 + a] + S[O_QS + e*64 + h*8 + a];
      s += siluf(q) * wa[h*8 + a];
    }
    S[O_LG + e*8 + h] = (S[O_VL + e] > 0.5f) ? s : -1e9f;

    const float step = 3.0f/127.0f;
    const float sigma = 3.0f/128.0f;
    for(int idx = t; idx < 2048; idx += 128){
      int ee = idx >> 7, i = idx & 127;
      float d = (S[O_LEN + ee] - step*(float)i) / sigma;
      S[O_RB + ee*132 + i] = expf(-0.5f*d*d);
    }
  }
  __syncthreads();

  // ---- P3: softmax per head over 16 edges ----
  if(t < 8){
    float m = -3e38f;
    for(int r=0;r<16;r++) m = fmaxf(m, S[O_LG + r*8 + t]);
    S[O_SX + t] = m;
  }
  __syncthreads();
  {
    float ex = expf(S[O_LG + t] - S[O_SX + (t & 7)]);
    __syncthreads();
    S[O_LG + t] = ex;
    __syncthreads();
    if(t < 8){
      float d = 0.f;
      for(int r=0;r<16;r++) d += S[O_LG + r*8 + t];
      S[O_SX + 8 + t] = d;
    }
    __syncthreads();
    S[O_AT + t] = ex / (S[O_SX + 8 + (t & 7)] + 1e-9f);
  }
  __syncthreads();

  // ---- P4: hid = silu(rbf @ We1 + b1); thread t = column, all 16 edges ----
  {
    float acc16[16];
    #pragma unroll
    for(int e=0;e<16;e++) acc16[e] = 0.f;
    for(int i4=0;i4<32;i4++){
      float w0 = We1[(i4*4+0)*128 + t];
      float w1 = We1[(i4*4+1)*128 + t];
      float w2 = We1[(i4*4+2)*128 + t];
      float w3 = We1[(i4*4+3)*128 + t];
      #pragma unroll
      for(int e=0;e<16;e++){
        float4 r = *(const float4*)&S[O_RB + e*132 + i4*4];
        acc16[e] += r.x*w0 + r.y*w1 + r.z*w2 + r.w*w3;
      }
    }
    float b = be1[t];
    #pragma unroll
    for(int e=0;e<16;e++) S[O_HD + e*132 + t] = siluf(acc16[e] + b);
  }
  __syncthreads();

  // ---- P5: eh = hid @ We2 + b2 ----
  {
    float acc16[16];
    #pragma unroll
    for(int e=0;e<16;e++) acc16[e] = 0.f;
    for(int i4=0;i4<32;i4++){
      float w0 = We2[(i4*4+0)*128 + t];
      float w1 = We2[(i4*4+1)*128 + t];
      float w2 = We2[(i4*4+2)*128 + t];
      float w3 = We2[(i4*4+3)*128 + t];
      #pragma unroll
      for(int e=0;e<16;e++){
        float4 h = *(const float4*)&S[O_HD + e*132 + i4*4];
        acc16[e] += h.x*w0 + h.y*w1 + h.z*w2 + h.w*w3;
      }
    }
    float b = be2[t];
    #pragma unroll
    for(int e=0;e<16;e++) S[O_EH + e*132 + t] = acc16[e] + b;
  }
  __syncthreads();

  // ---- P6: aggregation. Rotations cancel exactly:
  //      agg[l,c] = sum_e Z[src_e, l, c] * eh[e,c] * attn[e, c>>4]
  float acc[9];
  #pragma unroll
  for(int l=0;l<9;l++) acc[l] = 0.f;
  #pragma unroll 4
  for(int e=0;e<16;e++){
    const float* zp = &Z[(size_t)(base + Si[O_KI + e])*1152 + t];
    float sc = S[O_EH + e*132 + t] * S[O_AT + e*8 + (t>>4)];
    #pragma unroll
    for(int l=0;l<9;l++) acc[l] = fmaf(zp[l*128], sc, acc[l]);
  }
  #pragma unroll
  for(int l=0;l<9;l++) S[O_AG + l*128 + t] = acc[l];
  __syncthreads();

  // ---- P7: x = emb + agg @ Wo ; rmsnorm*g2 -> HL ----
  float x[9];
  #pragma unroll
  for(int l=0;l<9;l++) x[l] = 0.f;
  for(int i4=0;i4<32;i4++){
    float w0 = Wo[(i4*4+0)*128 + t];
    float w1 = Wo[(i4*4+1)*128 + t];
    float w2 = Wo[(i4*4+2)*128 + t];
    float w3 = Wo[(i4*4+3)*128 + t];
    #pragma unroll
    for(int l=0;l<9;l++){
      float4 a4 = *(const float4*)&S[O_AG + l*128 + i4*4];
      x[l] += a4.x*w0 + a4.y*w1 + a4.z*w2 + a4.w*w3;
    }
  }
  #pragma unroll
  for(int l=0;l<9;l++){
    x[l] += emb[(size_t)n*1152 + l*128 + t];
    S[O_RED + l*128 + t] = x[l]*x[l];
  }
  __syncthreads();
  if(t < 9){
    float s = 0.f;
    for(int i=0;i<128;i++) s += S[O_RED + t*128 + i];
    S[O_SS + t] = sqrtf(s/128.f + 1e-6f);
  }
  __syncthreads();
  {
    float g2c = g2[t];
    #pragma unroll
    for(int l=0;l<9;l++) S[O_HL + l*132 + t] = x[l]/S[O_SS + l]*g2c;
  }
  __syncthreads();

  // ---- P8: gate + hf = (h @ Wf1)*gate -> HF ----
  {
    float ga0 = 0.f, ga1 = 0.f;
    for(int c4=0;c4<32;c4++){
      float4 h4 = *(const float4*)&S[O_HL + c4*4];
      ga0 += h4.x*Wg[(c4*4+0)*256 + t] + h4.y*Wg[(c4*4+1)*256 + t]
           + h4.z*Wg[(c4*4+2)*256 + t] + h4.w*Wg[(c4*4+3)*256 + t];
      ga1 += h4.x*Wg[(c4*4+0)*256 + t + 128] + h4.y*Wg[(c4*4+1)*256 + t + 128]
           + h4.z*Wg[(c4*4+2)*256 + t + 128] + h4.w*Wg[(c4*4+3)*256 + t + 128];
    }
    float gate0 = siluf(ga0), gate1 = siluf(ga1);
    float f0[9], f1[9];
    #pragma unroll
    for(int l=0;l<9;l++){ f0[l]=0.f; f1[l]=0.f; }
    for(int c4=0;c4<32;c4++){
      float w0a = Wf1[(c4*4+0)*256 + t], w0b = Wf1[(c4*4+0)*256 + t + 128];
      float w1a = Wf1[(c4*4+1)*256 + t], w1b = Wf1[(c4*4+1)*256 + t + 128];
      float w2a = Wf1[(c4*4+2)*256 + t], w2b = Wf1[(c4*4+2)*256 + t + 128];
      float w3a = Wf1[(c4*4+3)*256 + t], w3b = Wf1[(c4*4+3)*256 + t + 128];
      #pragma unroll
      for(int l=0;l<9;l++){
        float4 h4 = *(const float4*)&S[O_HL + l*132 + c4*4];
        f0[l] += h4.x*w0a + h4.y*w1a + h4.z*w2a + h4.w*w3a;
        f1[l] += h4.x*w0b + h4.y*w1b + h4.z*w2b + h4.w*w3b;
      }
    }
    __syncthreads();   // HL reads done before HF overwrites region A
    #pragma unroll
    for(int l=0;l<9;l++){
      S[O_HF + l*260 + t]       = f0[l]*gate0;
      S[O_HF + l*260 + t + 128] = f1[l]*gate1;
    }
  }
  __syncthreads();

  // ---- P9: x += hf @ Wf2 ----
  for(int f4=0;f4<64;f4++){
    float w0 = Wf2[(f4*4+0)*128 + t];
    float w1 = Wf2[(f4*4+1)*128 + t];
    float w2 = Wf2[(f4*4+2)*128 + t];
    float w3 = Wf2[(f4*4+3)*128 + t];
    #pragma unroll
    for(int l=0;l<9;l++){
      float4 h4 = *(const float4*)&S[O_HF + l*260 + f4*4];
      x[l] += h4.x*w0 + h4.y*w1 + h4.z*w2 + h4.w*w3;
    }
  }
  __syncthreads();

  // ---- P10: final rmsnorm ----
  #pragma unroll
  for(int l=0;l<9;l++) S[O_RED + l*128 + t] = x[l]*x[l];
  __syncthreads();
  if(t < 9){
    float s = 0.f;
    for(int i=0;i<128;i++) s += S[O_RED + t*128 + i];
    S[O_SS + t] = sqrtf(s/128.f + 1e-6f);
  }
  __syncthreads();

  // ---- P11: apply precomputed film + store (f32) ----
  {
    float g1c = g1[t];
    int b = n >> 10;
    #pragma unroll
    for(int l=0;l<9;l++){
      int j = l*128 + t;
      float w  = filmG[b*2304 + j];
      float bi = filmG[b*2304 + 1152 + j];
      float y = x[l]/S[O_SS + l]*g1c;
      out[12288 + (size_t)n*1152 + j] = y*w + bi;
    }
  }
}

// ---------- K3: coords (exact f32 copy) + batch (= n>>10, f32) ----------
__global__ __launch_bounds__(256) void k_copy(const float* __restrict__ coord,
                                              float* __restrict__ out){
  int i = blockIdx.x*256 + threadIdx.x;
  if(i < 12288) out[i] = coord[i];
  int n = i - 12288;
  if(n >= 0 && n < 4096) out[12288 + 4718592 + n] = (float)(n >> 10);
}

extern "C" void kernel_launch(void* const* d_in, const int* in_sizes, int n_in,
                              void* d_out, int out_size, void* d_ws, size_t ws_size,
                              hipStream_t stream) {
  const float* coord = (const float*)d_in[0];
  const float* emb   = (const float*)d_in[1];
  const float* cond  = (const float*)d_in[3];
  const float* We1   = (const float*)d_in[4];
  const float* be1   = (const float*)d_in[5];
  const float* We2   = (const float*)d_in[6];
  const float* be2   = (const float*)d_in[7];
  const float* Wsrc  = (const float*)d_in[8];
  const float* Wdst  = (const float*)d_in[9];
  const float* wa    = (const float*)d_in[10];
  const float* Wv    = (const float*)d_in[11];
  const float* Wo    = (const float*)d_in[12];
  const float* g1    = (const float*)d_in[13];
  const float* g2    = (const float*)d_in[14];
  const float* Wg    = (const float*)d_in[15];
  const float* Wf1   = (const float*)d_in[16];
  const float* Wf2   = (const float*)d_in[17];
  const float* Wfilm = (const float*)d_in[18];
  const float* bfilm = (const float*)d_in[19];

  float* outf  = (float*)d_out;
  // workspace layout (floats):
  //   filmG : 4 x 2304            =     9,216
  //   QsG   : 4096 x 64           =   262,144
  //   QdG   : 4096 x 64           =   262,144
  //   ZG    : 4096 x 9 x 128      = 4,718,592
  // total 5,252,096 floats = ~21.0 MB
  float* filmG = (float*)d_ws;
  float* QsG   = filmG + 9216;
  float* QdG   = QsG + 262144;
  float* ZG    = QdG + 262144;

  k_film<<<dim3(9,4), 256, 0, stream>>>(cond, Wfilm, bfilm, filmG);
  k_pre<<<NNODE, 128, 0, stream>>>(emb, Wv, Wsrc, Wdst, ZG, QsG, QdG);
  k_node<<<NNODE, 128, 0, stream>>>(coord, emb,
                                    We1, be1, We2, be2, wa,
                                    Wo, g1, g2, Wg, Wf1, Wf2,
                                    QsG, QdG, ZG,
                                    filmG, outf);
  k_copy<<<64, 256, 0, stream>>>(coord, outf);
}

// Round 2
// 783.389 us; speedup vs baseline: 1.8457x; 1.0662x over previous
//
#include <hip/hip_runtime.h>

#define NNODE 4096
#define NPB   1024

__device__ __forceinline__ float siluf(float x){ return x / (1.0f + expf(-x)); }

// ---------------- LDS layout ----------------
// Shared: CRD @ 0 (3072 floats), live only during P0 (KNN); aliases node pools.
// Per-node pool (NPF floats), node h at offset h*NPF:
//   P1-P3 : QS@0(1024) QD@1024(64) LG@1088(128) SX@1216(16)
//   P2-P4 : RBW@2048(256)
//   P4-P5 : HD@0(2048)
//   P5-P6 : EH@2304(2048)
//   P6-P7 : AG@0(1152)
//   P7,P10: RED@1152(1152)
//   P7-P8 : HL@4352(1152)
//   P8-P9 : HF@0(2304)
//   smalls: AT@5504(128) KI@5632(16i) KD@5648 LEN@5664 VL@5680 W0@5696(16i) SS@5712
#define NPF   5744
#define P_QS   0
#define P_QD   1024
#define P_LG   1088
#define P_SX   1216
#define P_RBW  2048
#define P_EH   2304
#define P_HD   0
#define P_AG   0
#define P_RED  1152
#define P_HL   4352
#define P_HF   0
#define P_AT   5504
#define P_KI   5632
#define P_KD   5648
#define P_LEN  5664
#define P_VL   5680
#define P_W0   5696
#define P_SS   5712

// ---------- K0: film = mish(cond) @ Wfilm + bfilm -> d_ws (4 x 2304 f32) ----------
__global__ __launch_bounds__(256) void k_film(const float* __restrict__ cond,
                                              const float* __restrict__ Wfilm,
                                              const float* __restrict__ bfilm,
                                              float* __restrict__ filmG){
  __shared__ float mL[256];
  int b = blockIdx.y;
  int t = threadIdx.x;
  int j = blockIdx.x*256 + t;
  float x = cond[b*256 + t];
  float sp = fmaxf(x, 0.f) + log1pf(expf(-fabsf(x)));
  mL[t] = x * tanhf(sp);
  __syncthreads();
  if(j >= 2304) return;
  float acc = bfilm[j];
  for(int i=0;i<256;i++) acc += mL[i] * Wfilm[i*2304 + j];
  filmG[b*2304 + j] = acc;
}

// ---------- K1: per-node precompute (rotations cancel => edge-invariant) ----------
// Z  = emb @ Wv  (N x 9 x 128); Qs = emb[:,0] @ Wsrc (N x 64); Qd = emb[:,0] @ Wdst
__global__ __launch_bounds__(128) void k_pre(const float* __restrict__ emb,
                                             const float* __restrict__ Wv,
                                             const float* __restrict__ Wsrc,
                                             const float* __restrict__ Wdst,
                                             float* __restrict__ ZG,
                                             float* __restrict__ QsG,
                                             float* __restrict__ QdG){
  __shared__ __align__(16) float Es[1152];
  const int n = blockIdx.x;
  const int t = threadIdx.x;
  {
    const float4* src = (const float4*)(emb + (size_t)n*1152);
    float4* dst = (float4*)Es;
    for(int idx=t; idx<288; idx+=128) dst[idx] = src[idx];
  }
  __syncthreads();
  float z[9];
  #pragma unroll
  for(int l=0;l<9;l++) z[l]=0.f;
  for(int c4=0;c4<32;c4++){
    float w0 = Wv[(c4*4+0)*128 + t];
    float w1 = Wv[(c4*4+1)*128 + t];
    float w2 = Wv[(c4*4+2)*128 + t];
    float w3 = Wv[(c4*4+3)*128 + t];
    #pragma unroll
    for(int l=0;l<9;l++){
      float4 x4 = *(const float4*)&Es[l*128 + c4*4];
      z[l] += x4.x*w0 + x4.y*w1 + x4.z*w2 + x4.w*w3;
    }
  }
  #pragma unroll
  for(int l=0;l<9;l++) ZG[(size_t)n*1152 + l*128 + t] = z[l];
  {
    const float* W = (t < 64) ? Wsrc : Wdst;
    const int col = t & 63;
    float q = 0.f;
    for(int c=0;c<128;c++) q += Es[c] * W[c*64 + col];
    if(t < 64) QsG[n*64 + col] = q;
    else       QdG[n*64 + col] = q;
  }
}

// ---------- K2: main kernel — 2 nodes per 256-thread block ----------
__global__ __launch_bounds__(256) void k_node(
    const float* __restrict__ coord,
    const float* __restrict__ emb,
    const float* __restrict__ We1, const float* __restrict__ be1,
    const float* __restrict__ We2, const float* __restrict__ be2,
    const float* __restrict__ wa,
    const float* __restrict__ Wo,
    const float* __restrict__ g1, const float* __restrict__ g2,
    const float* __restrict__ Wg, const float* __restrict__ Wf1,
    const float* __restrict__ Wf2,
    const float* __restrict__ Qs, const float* __restrict__ Qd,
    const float* __restrict__ Z,
    const float* __restrict__ filmG,
    float* __restrict__ out){
  __shared__ __align__(16) float S[2*NPF];
  int* Si = (int*)S;
  const int t = threadIdx.x;
  const int h = t >> 7;          // node half: 0 or 1
  const int u = t & 127;         // lane within node
  const int n = blockIdx.x*2 + h;
  const int base = n & ~(NPB - 1);   // same for both halves (NPB even)
  const int self = n - base;
  const int NP = h * NPF;

  // ---- P0: stage coords once (shared); waves 0 & 2 do the two KNNs ----
  for(int idx = t; idx < 3072; idx += 256) S[idx] = coord[base*3 + idx];
  __syncthreads();
  const float cx = S[self*3+0];
  const float cy = S[self*3+1];
  const float cz = S[self*3+2];
  if((t & 64) == 0){
    int lane = t & 63;
    float d2a[16]; int ida[16];
    for(int q=0;q<16;q++){
      int j = lane + q*64;
      float dx = __fsub_rn(S[j*3+0], cx);
      float dy = __fsub_rn(S[j*3+1], cy);
      float dz = __fsub_rn(S[j*3+2], cz);
      float d2 = __fadd_rn(__fadd_rn(__fmul_rn(dx,dx), __fmul_rn(dy,dy)), __fmul_rn(dz,dz));
      if(j == self) d2 = 3e38f;
      d2a[q] = d2; ida[q] = j;
    }
    for(int r=0;r<16;r++){
      float bd = d2a[0]; int bi = ida[0];
      for(int q=1;q<16;q++){
        bool bet = (d2a[q] < bd) || (d2a[q] == bd && ida[q] < bi);
        if(bet){ bd = d2a[q]; bi = ida[q]; }
      }
      for(int s=1;s<64;s<<=1){
        float od = __shfl_xor(bd, s, 64);
        int   oi = __shfl_xor(bi, s, 64);
        bool bet = (od < bd) || (od == bd && oi < bi);
        if(bet){ bd = od; bi = oi; }
      }
      if(lane == 0){ Si[NP + P_KI + r] = bi; S[NP + P_KD + r] = bd; }
      for(int q=0;q<16;q++) if(ida[q] == bi) d2a[q] = 3e38f;
    }
  }
  __syncthreads();

  // ---- P1: len/valid/window-base (u<16) + stage Qs[src] + Qd[n] ----
  if(u < 16){
    float len = __fsqrt_rn(S[NP + P_KD + u]);
    S[NP + P_LEN + u] = len;
    S[NP + P_VL + u]  = (len <= 3.0f) ? 1.0f : 0.0f;
    int i0 = (int)(len * (127.0f/3.0f) + 0.5f);
    int w0 = i0 - 7;
    w0 = w0 < 0 ? 0 : (w0 > 112 ? 112 : w0);
    Si[NP + P_W0 + u] = w0;
  }
  for(int idx = u; idx < 1024; idx += 128){
    int e = idx >> 6, ha = idx & 63;
    int src = base + Si[NP + P_KI + e];
    S[NP + P_QS + idx] = Qs[src*64 + ha];
  }
  if(u < 64) S[NP + P_QD + u] = Qd[n*64 + u];
  __syncthreads();

  // ---- P2: logits (e=u>>3, head=u&7) + windowed rbf (16 bins/edge) ----
  {
    int e = u >> 3, hh = u & 7;
    float s = 0.f;
    #pragma unroll
    for(int a=0;a<8;a++){
      float q = S[NP + P_QD + hh*8 + a] + S[NP + P_QS + e*64 + hh*8 + a];
      s += siluf(q) * wa[hh*8 + a];
    }
    S[NP + P_LG + u] = (S[NP + P_VL + e] > 0.5f) ? s : -1e9f;

    const float step = 3.0f/127.0f;
    const float sigma = 3.0f/128.0f;
    for(int idx = u; idx < 256; idx += 128){
      int e2 = idx >> 4, w = idx & 15;
      int bin = Si[NP + P_W0 + e2] + w;
      float d = (S[NP + P_LEN + e2] - step*(float)bin) / sigma;
      S[NP + P_RBW + idx] = expf(-0.5f*d*d);
    }
  }
  __syncthreads();

  // ---- P3: softmax per head over 16 edges ----
  if(u < 8){
    float m = -3e38f;
    for(int r=0;r<16;r++) m = fmaxf(m, S[NP + P_LG + r*8 + u]);
    S[NP + P_SX + u] = m;
  }
  __syncthreads();
  {
    float ex = expf(S[NP + P_LG + u] - S[NP + P_SX + (u & 7)]);
    __syncthreads();
    S[NP + P_LG + u] = ex;
    __syncthreads();
    if(u < 8){
      float d = 0.f;
      for(int r=0;r<16;r++) d += S[NP + P_LG + r*8 + u];
      S[NP + P_SX + 8 + u] = d;
    }
    __syncthreads();
    S[NP + P_AT + u] = ex / (S[NP + P_SX + 8 + (u & 7)] + 1e-9f);
  }
  __syncthreads();

  // ---- P4: hid = silu(rbf @ We1 + b1), 16-bin window per edge ----
  {
    float acc16[16];
    int   b0[16];
    #pragma unroll
    for(int e=0;e<16;e++){ acc16[e] = 0.f; b0[e] = Si[NP + P_W0 + e]; }
    for(int w=0; w<16; w++){
      #pragma unroll
      for(int e=0;e<16;e++){
        float rb = S[NP + P_RBW + e*16 + w];
        acc16[e] = fmaf(rb, We1[(b0[e] + w)*128 + u], acc16[e]);
      }
    }
    float b = be1[u];
    #pragma unroll
    for(int e=0;e<16;e++) S[NP + P_HD + e*128 + u] = siluf(acc16[e] + b);
  }
  __syncthreads();

  // ---- P5: eh = hid @ We2 + b2 ----
  {
    float acc16[16];
    #pragma unroll
    for(int e=0;e<16;e++) acc16[e] = 0.f;
    for(int i4=0;i4<32;i4++){
      float w0 = We2[(i4*4+0)*128 + u];
      float w1 = We2[(i4*4+1)*128 + u];
      float w2 = We2[(i4*4+2)*128 + u];
      float w3 = We2[(i4*4+3)*128 + u];
      #pragma unroll
      for(int e=0;e<16;e++){
        float4 h4 = *(const float4*)&S[NP + P_HD + e*128 + i4*4];
        acc16[e] += h4.x*w0 + h4.y*w1 + h4.z*w2 + h4.w*w3;
      }
    }
    float b = be2[u];
    #pragma unroll
    for(int e=0;e<16;e++) S[NP + P_EH + e*128 + u] = acc16[e] + b;
  }
  __syncthreads();

  // ---- P6: aggregation (rotations cancel):
  //      agg[l,c] = sum_e Z[src_e, l, c] * eh[e,c] * attn[e, c>>4]
  float acc[9];
  #pragma unroll
  for(int l=0;l<9;l++) acc[l] = 0.f;
  #pragma unroll 4
  for(int e=0;e<16;e++){
    const float* zp = &Z[(size_t)(base + Si[NP + P_KI + e])*1152 + u];
    float sc = S[NP + P_EH + e*128 + u] * S[NP + P_AT + e*8 + (u>>4)];
    #pragma unroll
    for(int l=0;l<9;l++) acc[l] = fmaf(zp[l*128], sc, acc[l]);
  }
  #pragma unroll
  for(int l=0;l<9;l++) S[NP + P_AG + l*128 + u] = acc[l];
  __syncthreads();

  // ---- P7: x = emb + agg @ Wo ; rmsnorm*g2 -> HL ----
  float x[9];
  #pragma unroll
  for(int l=0;l<9;l++) x[l] = 0.f;
  for(int i4=0;i4<32;i4++){
    float w0 = Wo[(i4*4+0)*128 + u];
    float w1 = Wo[(i4*4+1)*128 + u];
    float w2 = Wo[(i4*4+2)*128 + u];
    float w3 = Wo[(i4*4+3)*128 + u];
    #pragma unroll
    for(int l=0;l<9;l++){
      float4 a4 = *(const float4*)&S[NP + P_AG + l*128 + i4*4];
      x[l] += a4.x*w0 + a4.y*w1 + a4.z*w2 + a4.w*w3;
    }
  }
  #pragma unroll
  for(int l=0;l<9;l++){
    x[l] += emb[(size_t)n*1152 + l*128 + u];
    S[NP + P_RED + l*128 + u] = x[l]*x[l];
  }
  __syncthreads();
  if(u < 9){
    float s = 0.f;
    for(int i=0;i<128;i++) s += S[NP + P_RED + u*128 + i];
    S[NP + P_SS + u] = sqrtf(s/128.f + 1e-6f);
  }
  __syncthreads();
  {
    float g2c = g2[u];
    #pragma unroll
    for(int l=0;l<9;l++) S[NP + P_HL + l*128 + u] = x[l]/S[NP + P_SS + l]*g2c;
  }
  __syncthreads();

  // ---- P8: gate + hf = (h @ Wf1)*gate -> HF ----
  {
    float ga0 = 0.f, ga1 = 0.f;
    for(int c4=0;c4<32;c4++){
      float4 h4 = *(const float4*)&S[NP + P_HL + c4*4];
      ga0 += h4.x*Wg[(c4*4+0)*256 + u] + h4.y*Wg[(c4*4+1)*256 + u]
           + h4.z*Wg[(c4*4+2)*256 + u] + h4.w*Wg[(c4*4+3)*256 + u];
      ga1 += h4.x*Wg[(c4*4+0)*256 + u + 128] + h4.y*Wg[(c4*4+1)*256 + u + 128]
           + h4.z*Wg[(c4*4+2)*256 + u + 128] + h4.w*Wg[(c4*4+3)*256 + u + 128];
    }
    float gate0 = siluf(ga0), gate1 = siluf(ga1);
    float f0[9], f1[9];
    #pragma unroll
    for(int l=0;l<9;l++){ f0[l]=0.f; f1[l]=0.f; }
    for(int c4=0;c4<32;c4++){
      float w0a = Wf1[(c4*4+0)*256 + u], w0b = Wf1[(c4*4+0)*256 + u + 128];
      float w1a = Wf1[(c4*4+1)*256 + u], w1b = Wf1[(c4*4+1)*256 + u + 128];
      float w2a = Wf1[(c4*4+2)*256 + u], w2b = Wf1[(c4*4+2)*256 + u + 128];
      float w3a = Wf1[(c4*4+3)*256 + u], w3b = Wf1[(c4*4+3)*256 + u + 128];
      #pragma unroll
      for(int l=0;l<9;l++){
        float4 h4 = *(const float4*)&S[NP + P_HL + l*128 + c4*4];
        f0[l] += h4.x*w0a + h4.y*w1a + h4.z*w2a + h4.w*w3a;
        f1[l] += h4.x*w0b + h4.y*w1b + h4.z*w2b + h4.w*w3b;
      }
    }
    // HF (0..2304) does not overlap HL (4352..5504): no mid-phase barrier needed
    #pragma unroll
    for(int l=0;l<9;l++){
      S[NP + P_HF + l*256 + u]       = f0[l]*gate0;
      S[NP + P_HF + l*256 + u + 128] = f1[l]*gate1;
    }
  }
  __syncthreads();

  // ---- P9: x += hf @ Wf2 ----
  for(int f4=0;f4<64;f4++){
    float w0 = Wf2[(f4*4+0)*128 + u];
    float w1 = Wf2[(f4*4+1)*128 + u];
    float w2 = Wf2[(f4*4+2)*128 + u];
    float w3 = Wf2[(f4*4+3)*128 + u];
    #pragma unroll
    for(int l=0;l<9;l++){
      float4 h4 = *(const float4*)&S[NP + P_HF + l*256 + f4*4];
      x[l] += h4.x*w0 + h4.y*w1 + h4.z*w2 + h4.w*w3;
    }
  }
  __syncthreads();

  // ---- P10: final rmsnorm ----
  #pragma unroll
  for(int l=0;l<9;l++) S[NP + P_RED + l*128 + u] = x[l]*x[l];
  __syncthreads();
  if(u < 9){
    float s = 0.f;
    for(int i=0;i<128;i++) s += S[NP + P_RED + u*128 + i];
    S[NP + P_SS + u] = sqrtf(s/128.f + 1e-6f);
  }
  __syncthreads();

  // ---- P11: apply precomputed film + store (f32) ----
  {
    float g1c = g1[u];
    int b = n >> 10;
    #pragma unroll
    for(int l=0;l<9;l++){
      int j = l*128 + u;
      float w  = filmG[b*2304 + j];
      float bi = filmG[b*2304 + 1152 + j];
      float y = x[l]/S[NP + P_SS + l]*g1c;
      out[12288 + (size_t)n*1152 + j] = y*w + bi;
    }
  }
}

// ---------- K3: coords (exact f32 copy) + batch (= n>>10, f32) ----------
__global__ __launch_bounds__(256) void k_copy(const float* __restrict__ coord,
                                              float* __restrict__ out){
  int i = blockIdx.x*256 + threadIdx.x;
  if(i < 12288) out[i] = coord[i];
  int n = i - 12288;
  if(n >= 0 && n < 4096) out[12288 + 4718592 + n] = (float)(n >> 10);
}

extern "C" void kernel_launch(void* const* d_in, const int* in_sizes, int n_in,
                              void* d_out, int out_size, void* d_ws, size_t ws_size,
                              hipStream_t stream) {
  const float* coord = (const float*)d_in[0];
  const float* emb   = (const float*)d_in[1];
  const float* cond  = (const float*)d_in[3];
  const float* We1   = (const float*)d_in[4];
  const float* be1   = (const float*)d_in[5];
  const float* We2   = (const float*)d_in[6];
  const float* be2   = (const float*)d_in[7];
  const float* Wsrc  = (const float*)d_in[8];
  const float* Wdst  = (const float*)d_in[9];
  const float* wa    = (const float*)d_in[10];
  const float* Wv    = (const float*)d_in[11];
  const float* Wo    = (const float*)d_in[12];
  const float* g1    = (const float*)d_in[13];
  const float* g2    = (const float*)d_in[14];
  const float* Wg    = (const float*)d_in[15];
  const float* Wf1   = (const float*)d_in[16];
  const float* Wf2   = (const float*)d_in[17];
  const float* Wfilm = (const float*)d_in[18];
  const float* bfilm = (const float*)d_in[19];

  float* outf  = (float*)d_out;
  // workspace (floats): filmG 9216 | QsG 262144 | QdG 262144 | ZG 4718592  (~21 MB)
  float* filmG = (float*)d_ws;
  float* QsG   = filmG + 9216;
  float* QdG   = QsG + 262144;
  float* ZG    = QdG + 262144;

  k_film<<<dim3(9,4), 256, 0, stream>>>(cond, Wfilm, bfilm, filmG);
  k_pre<<<NNODE, 128, 0, stream>>>(emb, Wv, Wsrc, Wdst, ZG, QsG, QdG);
  k_node<<<NNODE/2, 256, 0, stream>>>(coord, emb,
                                      We1, be1, We2, be2, wa,
                                      Wo, g1, g2, Wg, Wf1, Wf2,
                                      QsG, QdG, ZG,
                                      filmG, outf);
  k_copy<<<64, 256, 0, stream>>>(coord, outf);
}

// Round 3
// 446.787 us; speedup vs baseline: 3.2362x; 1.7534x over previous
//
#include <hip/hip_runtime.h>

#define NNODE 4096
#define NPB   1024

__device__ __forceinline__ float siluf(float x){ return x / (1.0f + expf(-x)); }

// ---------- K0: film = mish(cond) @ Wfilm + bfilm -> d_ws (4 x 2304 f32) ----------
__global__ __launch_bounds__(256) void k_film(const float* __restrict__ cond,
                                              const float* __restrict__ Wfilm,
                                              const float* __restrict__ bfilm,
                                              float* __restrict__ filmG){
  __shared__ float mL[256];
  int b = blockIdx.y;
  int t = threadIdx.x;
  int j = blockIdx.x*256 + t;
  float x = cond[b*256 + t];
  float sp = fmaxf(x, 0.f) + log1pf(expf(-fabsf(x)));
  mL[t] = x * tanhf(sp);
  __syncthreads();
  if(j >= 2304) return;
  float acc = bfilm[j];
  for(int i=0;i<256;i++) acc += mL[i] * Wfilm[i*2304 + j];
  filmG[b*2304 + j] = acc;
}

// ---------- K1: per-node precompute (rotations cancel => edge-invariant) ----------
__global__ __launch_bounds__(128) void k_pre(const float* __restrict__ emb,
                                             const float* __restrict__ Wv,
                                             const float* __restrict__ Wsrc,
                                             const float* __restrict__ Wdst,
                                             float* __restrict__ ZG,
                                             float* __restrict__ QsG,
                                             float* __restrict__ QdG){
  __shared__ __align__(16) float Es[1152];
  const int n = blockIdx.x;
  const int t = threadIdx.x;
  {
    const float4* src = (const float4*)(emb + (size_t)n*1152);
    float4* dst = (float4*)Es;
    for(int idx=t; idx<288; idx+=128) dst[idx] = src[idx];
  }
  __syncthreads();
  float z[9];
  #pragma unroll
  for(int l=0;l<9;l++) z[l]=0.f;
  for(int c4=0;c4<32;c4++){
    float w0 = Wv[(c4*4+0)*128 + t];
    float w1 = Wv[(c4*4+1)*128 + t];
    float w2 = Wv[(c4*4+2)*128 + t];
    float w3 = Wv[(c4*4+3)*128 + t];
    #pragma unroll
    for(int l=0;l<9;l++){
      float4 x4 = *(const float4*)&Es[l*128 + c4*4];
      z[l] += x4.x*w0 + x4.y*w1 + x4.z*w2 + x4.w*w3;
    }
  }
  #pragma unroll
  for(int l=0;l<9;l++) ZG[(size_t)n*1152 + l*128 + t] = z[l];
  {
    const float* W = (t < 64) ? Wsrc : Wdst;
    const int col = t & 63;
    float q = 0.f;
    for(int c=0;c<128;c++) q += Es[c] * W[c*64 + col];
    if(t < 64) QsG[n*64 + col] = q;
    else       QdG[n*64 + col] = q;
  }
}

// ---------------- K2: edge kernel — 2 nodes per 256-thread block ----------------
// Per-node pool (E_NPF floats). CRD (3072) aliases absolute S[0..3072], dead after P0.
#define E_HD   0     /* 2048: hid, P4->P5; aliases QS/QD/LG/SX (dead by P4) */
#define E_QS   0     /* 1024, P1->P2 */
#define E_QD   1024  /* 64 */
#define E_LG   1088  /* 128 */
#define E_SX   1216  /* 16 */
#define E_EH   2048  /* 2048: eh, P5->P6 */
#define E_RBW  4096  /* 256 */
#define E_AT   4352  /* 128 */
#define E_KI   4480  /* 16 ints */
#define E_KD   4496
#define E_LEN  4512
#define E_VL   4528
#define E_W0   4544
#define E_NPF  4608
__global__ __launch_bounds__(256) void k_edge(
    const float* __restrict__ coord,
    const float* __restrict__ We1, const float* __restrict__ be1,
    const float* __restrict__ We2, const float* __restrict__ be2,
    const float* __restrict__ wa,
    const float* __restrict__ Qs, const float* __restrict__ Qd,
    const float* __restrict__ Z,
    float* __restrict__ out){
  __shared__ __align__(16) float S[2*E_NPF];
  int* Si = (int*)S;
  const int t = threadIdx.x;
  const int h = t >> 7;
  const int u = t & 127;
  const int n = blockIdx.x*2 + h;
  const int base = n & ~(NPB - 1);
  const int self = n - base;
  const int NP = h * E_NPF;
  float* aggG = out + 12288;

  // ---- P0: stage coords once; waves 0 & 2 do the two KNNs ----
  for(int idx = t; idx < 3072; idx += 256) S[idx] = coord[base*3 + idx];
  __syncthreads();
  const float cx = S[self*3+0];
  const float cy = S[self*3+1];
  const float cz = S[self*3+2];
  if((t & 64) == 0){
    int lane = t & 63;
    float d2a[16]; int ida[16];
    for(int q=0;q<16;q++){
      int j = lane + q*64;
      float dx = __fsub_rn(S[j*3+0], cx);
      float dy = __fsub_rn(S[j*3+1], cy);
      float dz = __fsub_rn(S[j*3+2], cz);
      float d2 = __fadd_rn(__fadd_rn(__fmul_rn(dx,dx), __fmul_rn(dy,dy)), __fmul_rn(dz,dz));
      if(j == self) d2 = 3e38f;
      d2a[q] = d2; ida[q] = j;
    }
    for(int r=0;r<16;r++){
      float bd = d2a[0]; int bi = ida[0];
      for(int q=1;q<16;q++){
        bool bet = (d2a[q] < bd) || (d2a[q] == bd && ida[q] < bi);
        if(bet){ bd = d2a[q]; bi = ida[q]; }
      }
      for(int s=1;s<64;s<<=1){
        float od = __shfl_xor(bd, s, 64);
        int   oi = __shfl_xor(bi, s, 64);
        bool bet = (od < bd) || (od == bd && oi < bi);
        if(bet){ bd = od; bi = oi; }
      }
      if(lane == 0){ Si[NP + E_KI + r] = bi; S[NP + E_KD + r] = bd; }
      for(int q=0;q<16;q++) if(ida[q] == bi) d2a[q] = 3e38f;
    }
  }
  __syncthreads();

  // ---- P1: len/valid/window (u<16) + stage Qs[src] + Qd[n] ----
  if(u < 16){
    float len = __fsqrt_rn(S[NP + E_KD + u]);
    S[NP + E_LEN + u] = len;
    S[NP + E_VL + u]  = (len <= 3.0f) ? 1.0f : 0.0f;
    int i0 = (int)(len * (127.0f/3.0f) + 0.5f);
    int w0 = i0 - 7;
    w0 = w0 < 0 ? 0 : (w0 > 112 ? 112 : w0);
    Si[NP + E_W0 + u] = w0;
  }
  for(int idx = u; idx < 1024; idx += 128){
    int e = idx >> 6, ha = idx & 63;
    int src = base + Si[NP + E_KI + e];
    S[NP + E_QS + idx] = Qs[src*64 + ha];
  }
  if(u < 64) S[NP + E_QD + u] = Qd[n*64 + u];
  __syncthreads();

  // ---- P2: logits + windowed rbf ----
  {
    int e = u >> 3, hh = u & 7;
    float s = 0.f;
    #pragma unroll
    for(int a=0;a<8;a++){
      float q = S[NP + E_QD + hh*8 + a] + S[NP + E_QS + e*64 + hh*8 + a];
      s += siluf(q) * wa[hh*8 + a];
    }
    S[NP + E_LG + u] = (S[NP + E_VL + e] > 0.5f) ? s : -1e9f;

    const float step = 3.0f/127.0f;
    const float sigma = 3.0f/128.0f;
    for(int idx = u; idx < 256; idx += 128){
      int e2 = idx >> 4, w = idx & 15;
      int bin = Si[NP + E_W0 + e2] + w;
      float d = (S[NP + E_LEN + e2] - step*(float)bin) / sigma;
      S[NP + E_RBW + idx] = expf(-0.5f*d*d);
    }
  }
  __syncthreads();

  // ---- P3: softmax per head over 16 edges ----
  if(u < 8){
    float m = -3e38f;
    for(int r=0;r<16;r++) m = fmaxf(m, S[NP + E_LG + r*8 + u]);
    S[NP + E_SX + u] = m;
  }
  __syncthreads();
  {
    float ex = expf(S[NP + E_LG + u] - S[NP + E_SX + (u & 7)]);
    __syncthreads();
    S[NP + E_LG + u] = ex;
    __syncthreads();
    if(u < 8){
      float d = 0.f;
      for(int r=0;r<16;r++) d += S[NP + E_LG + r*8 + u];
      S[NP + E_SX + 8 + u] = d;
    }
    __syncthreads();
    S[NP + E_AT + u] = ex / (S[NP + E_SX + 8 + (u & 7)] + 1e-9f);
  }
  __syncthreads();

  // ---- P4: hid = silu(rbf @ We1 + b1), 16-bin window per edge -> HD ----
  {
    float acc16[16];
    int   b0[16];
    #pragma unroll
    for(int e=0;e<16;e++){ acc16[e] = 0.f; b0[e] = Si[NP + E_W0 + e]; }
    for(int w=0; w<16; w++){
      #pragma unroll
      for(int e=0;e<16;e++){
        float rb = S[NP + E_RBW + e*16 + w];
        acc16[e] = fmaf(rb, We1[(b0[e] + w)*128 + u], acc16[e]);
      }
    }
    float b = be1[u];
    #pragma unroll
    for(int e=0;e<16;e++) S[NP + E_HD + e*128 + u] = siluf(acc16[e] + b);
  }
  __syncthreads();

  // ---- P5: eh = hid @ We2 + b2 -> EH ----
  {
    float acc16[16];
    #pragma unroll
    for(int e=0;e<16;e++) acc16[e] = 0.f;
    for(int i4=0;i4<32;i4++){
      float w0 = We2[(i4*4+0)*128 + u];
      float w1 = We2[(i4*4+1)*128 + u];
      float w2 = We2[(i4*4+2)*128 + u];
      float w3 = We2[(i4*4+3)*128 + u];
      #pragma unroll
      for(int e=0;e<16;e++){
        float4 h4 = *(const float4*)&S[NP + E_HD + e*128 + i4*4];
        acc16[e] += h4.x*w0 + h4.y*w1 + h4.z*w2 + h4.w*w3;
      }
    }
    float b = be2[u];
    #pragma unroll
    for(int e=0;e<16;e++) S[NP + E_EH + e*128 + u] = acc16[e] + b;
  }
  __syncthreads();

  // ---- P6: agg[l,c] = sum_e Z[src_e,l,c] * eh[e,c] * attn[e,c>>4] -> aggG ----
  {
    float acc[9];
    #pragma unroll
    for(int l=0;l<9;l++) acc[l] = 0.f;
    #pragma unroll 4
    for(int e=0;e<16;e++){
      const float* zp = &Z[(size_t)(base + Si[NP + E_KI + e])*1152 + u];
      float sc = S[NP + E_EH + e*128 + u] * S[NP + E_AT + e*8 + (u>>4)];
      #pragma unroll
      for(int l=0;l<9;l++) acc[l] = fmaf(zp[l*128], sc, acc[l]);
    }
    #pragma unroll
    for(int l=0;l<9;l++) aggG[(size_t)n*1152 + l*128 + u] = acc[l];
  }
}

// ---------------- K3: batched FFN — 4 nodes per 256-thread block ----------------
#define FF_AHL 0      /* 4608: AGG tile, then HL tile (36 rows x 128) */
#define FF_HID 4608   /* 2 x 2304: double-buffered hid tile (36 x 64) */
#define FF_RED 9216   /* 72: rms partials */
#define FF_NLDS 9296
__global__ __launch_bounds__(256) void k_ffn(
    const float* __restrict__ emb,
    const float* __restrict__ Wo,
    const float* __restrict__ g1, const float* __restrict__ g2,
    const float* __restrict__ Wg, const float* __restrict__ Wf1,
    const float* __restrict__ Wf2,
    const float* __restrict__ filmG,
    float* __restrict__ out){
  __shared__ __align__(16) float S[FF_NLDS];
  const int t = threadIdx.x;
  const int n0 = blockIdx.x * 4;
  float* aggG = out + 12288;

  // stage agg tile (4 nodes contiguous = 4608 floats)
  {
    const float4* src = (const float4*)(aggG + (size_t)n0*1152);
    float4* dst = (float4*)&S[FF_AHL];
    for(int i=t;i<1152;i+=256) dst[i] = src[i];
  }
  __syncthreads();

  const int u = t & 127, g = t >> 7;
  float x[2][9];
  #pragma unroll
  for(int j=0;j<2;j++)
    #pragma unroll
    for(int l=0;l<9;l++) x[j][l]=0.f;

  // GEMM1: x = AGG @ Wo
  for(int c4=0;c4<32;c4++){
    float w0 = Wo[(c4*4+0)*128+u];
    float w1 = Wo[(c4*4+1)*128+u];
    float w2 = Wo[(c4*4+2)*128+u];
    float w3 = Wo[(c4*4+3)*128+u];
    #pragma unroll
    for(int j=0;j<2;j++)
      #pragma unroll
      for(int l=0;l<9;l++){
        float4 a4 = *(const float4*)&S[FF_AHL + ((2*g+j)*9+l)*128 + c4*4];
        x[j][l] += a4.x*w0 + a4.y*w1 + a4.z*w2 + a4.w*w3;
      }
  }

  // += emb; rms partials (shfl within wave, 2 wave-partials per row in LDS)
  #pragma unroll
  for(int j=0;j<2;j++)
    #pragma unroll
    for(int l=0;l<9;l++){
      x[j][l] += emb[(size_t)(n0+2*g+j)*1152 + l*128 + u];
      float sq = x[j][l]*x[j][l];
      #pragma unroll
      for(int s=1;s<64;s<<=1) sq += __shfl_xor(sq, s, 64);
      if((u&63)==0) S[FF_RED + ((2*g+j)*9+l)*2 + (u>>6)] = sq;
    }
  __syncthreads();

  // HL = x/ss*g2 -> overwrite AGG region
  {
    float g2u = g2[u];
    #pragma unroll
    for(int j=0;j<2;j++)
      #pragma unroll
      for(int l=0;l<9;l++){
        int r = (2*g+j)*9+l;
        float s = S[FF_RED + r*2] + S[FF_RED + r*2+1];
        float ss = sqrtf(s/128.f + 1e-6f);
        S[FF_AHL + r*128 + u] = x[j][l]/ss*g2u;
      }
  }
  __syncthreads();

  // f-tile loop: GEMM2 (gate + hid tile) then GEMM3 (x += hid @ Wf2)
  const int fc = t & 63, rg = t >> 6;
  for(int ft=0; ft<4; ft++){
    const int f0 = ft*64;
    float ha[9]; float gacc = 0.f;
    #pragma unroll
    for(int l=0;l<9;l++) ha[l]=0.f;
    for(int c4=0;c4<32;c4++){
      float wg0=Wg[(c4*4+0)*256+f0+fc], wg1=Wg[(c4*4+1)*256+f0+fc],
            wg2=Wg[(c4*4+2)*256+f0+fc], wg3=Wg[(c4*4+3)*256+f0+fc];
      float wa0=Wf1[(c4*4+0)*256+f0+fc], wa1=Wf1[(c4*4+1)*256+f0+fc],
            wa2=Wf1[(c4*4+2)*256+f0+fc], wa3=Wf1[(c4*4+3)*256+f0+fc];
      float4 h0 = *(const float4*)&S[FF_AHL + (rg*9+0)*128 + c4*4];
      gacc  += h0.x*wg0 + h0.y*wg1 + h0.z*wg2 + h0.w*wg3;
      ha[0] += h0.x*wa0 + h0.y*wa1 + h0.z*wa2 + h0.w*wa3;
      #pragma unroll
      for(int l=1;l<9;l++){
        float4 h4 = *(const float4*)&S[FF_AHL + (rg*9+l)*128 + c4*4];
        ha[l] += h4.x*wa0 + h4.y*wa1 + h4.z*wa2 + h4.w*wa3;
      }
    }
    {
      float gate = siluf(gacc);
      float* hb = &S[FF_HID + (ft&1)*2304];
      #pragma unroll
      for(int l=0;l<9;l++) hb[(rg*9+l)*64 + fc] = ha[l]*gate;
    }
    __syncthreads();
    const float* hbr = &S[FF_HID + (ft&1)*2304];
    for(int f4=0; f4<16; f4++){
      float w0 = Wf2[(f0+f4*4+0)*128 + u];
      float w1 = Wf2[(f0+f4*4+1)*128 + u];
      float w2 = Wf2[(f0+f4*4+2)*128 + u];
      float w3 = Wf2[(f0+f4*4+3)*128 + u];
      #pragma unroll
      for(int j=0;j<2;j++)
        #pragma unroll
        for(int l=0;l<9;l++){
          float4 h4 = *(const float4*)&hbr[((2*g+j)*9+l)*64 + f4*4];
          x[j][l] += h4.x*w0 + h4.y*w1 + h4.z*w2 + h4.w*w3;
        }
    }
  }

  // final rms
  #pragma unroll
  for(int j=0;j<2;j++)
    #pragma unroll
    for(int l=0;l<9;l++){
      float sq = x[j][l]*x[j][l];
      #pragma unroll
      for(int s=1;s<64;s<<=1) sq += __shfl_xor(sq, s, 64);
      if((u&63)==0) S[FF_RED + ((2*g+j)*9+l)*2 + (u>>6)] = sq;
    }
  __syncthreads();

  // film + store
  {
    float g1u = g1[u];
    int b = n0 >> 10;
    #pragma unroll
    for(int j=0;j<2;j++)
      #pragma unroll
      for(int l=0;l<9;l++){
        int r = (2*g+j)*9+l;
        float s = S[FF_RED + r*2] + S[FF_RED + r*2+1];
        float ss = sqrtf(s/128.f + 1e-6f);
        int jj = l*128 + u;
        float w  = filmG[b*2304 + jj];
        float bi = filmG[b*2304 + 1152 + jj];
        float y = x[j][l]/ss*g1u;
        out[12288 + (size_t)(n0+2*g+j)*1152 + jj] = y*w + bi;
      }
  }
}

// ---------- K4: coords (exact f32 copy) + batch (= n>>10, f32) ----------
__global__ __launch_bounds__(256) void k_copy(const float* __restrict__ coord,
                                              float* __restrict__ out){
  int i = blockIdx.x*256 + threadIdx.x;
  if(i < 12288) out[i] = coord[i];
  int n = i - 12288;
  if(n >= 0 && n < 4096) out[12288 + 4718592 + n] = (float)(n >> 10);
}

extern "C" void kernel_launch(void* const* d_in, const int* in_sizes, int n_in,
                              void* d_out, int out_size, void* d_ws, size_t ws_size,
                              hipStream_t stream) {
  const float* coord = (const float*)d_in[0];
  const float* emb   = (const float*)d_in[1];
  const float* cond  = (const float*)d_in[3];
  const float* We1   = (const float*)d_in[4];
  const float* be1   = (const float*)d_in[5];
  const float* We2   = (const float*)d_in[6];
  const float* be2   = (const float*)d_in[7];
  const float* Wsrc  = (const float*)d_in[8];
  const float* Wdst  = (const float*)d_in[9];
  const float* wa    = (const float*)d_in[10];
  const float* Wv    = (const float*)d_in[11];
  const float* Wo    = (const float*)d_in[12];
  const float* g1    = (const float*)d_in[13];
  const float* g2    = (const float*)d_in[14];
  const float* Wg    = (const float*)d_in[15];
  const float* Wf1   = (const float*)d_in[16];
  const float* Wf2   = (const float*)d_in[17];
  const float* Wfilm = (const float*)d_in[18];
  const float* bfilm = (const float*)d_in[19];

  float* outf  = (float*)d_out;
  // workspace (floats): filmG 9216 | QsG 262144 | QdG 262144 | ZG 4718592 (~21 MB)
  // agg lives in the out buffer (out+12288), consumed in-place by k_ffn.
  float* filmG = (float*)d_ws;
  float* QsG   = filmG + 9216;
  float* QdG   = QsG + 262144;
  float* ZG    = QdG + 262144;

  k_film<<<dim3(9,4), 256, 0, stream>>>(cond, Wfilm, bfilm, filmG);
  k_pre<<<NNODE, 128, 0, stream>>>(emb, Wv, Wsrc, Wdst, ZG, QsG, QdG);
  k_edge<<<NNODE/2, 256, 0, stream>>>(coord, We1, be1, We2, be2, wa,
                                      QsG, QdG, ZG, outf);
  k_ffn<<<NNODE/4, 256, 0, stream>>>(emb, Wo, g1, g2, Wg, Wf1, Wf2,
                                     filmG, outf);
  k_copy<<<64, 256, 0, stream>>>(coord, outf);
}

// Round 4
// 442.649 us; speedup vs baseline: 3.2665x; 1.0093x over previous
//
#include <hip/hip_runtime.h>

#define NNODE 4096
#define NPB   1024

__device__ __forceinline__ float siluf(float x){ return x / (1.0f + expf(-x)); }

// ---------- K0: film = mish(cond) @ Wfilm + bfilm -> d_ws (4 x 2304 f32) ----------
__global__ __launch_bounds__(256) void k_film(const float* __restrict__ cond,
                                              const float* __restrict__ Wfilm,
                                              const float* __restrict__ bfilm,
                                              float* __restrict__ filmG){
  __shared__ float mL[256];
  int b = blockIdx.y;
  int t = threadIdx.x;
  int j = blockIdx.x*256 + t;
  float x = cond[b*256 + t];
  float sp = fmaxf(x, 0.f) + log1pf(expf(-fabsf(x)));
  mL[t] = x * tanhf(sp);
  __syncthreads();
  if(j >= 2304) return;
  float acc = bfilm[j];
  for(int i=0;i<256;i++) acc += mL[i] * Wfilm[i*2304 + j];
  filmG[b*2304 + j] = acc;
}

// ---------- K1: per-node precompute (rotations cancel => edge-invariant) ----------
// wave0: l rows 0..4, wave1: rows 4..8 (row 4 duplicated, identical value).
// Lane owns column pair (2*u2, 2*u2+1).
__global__ __launch_bounds__(128) void k_pre(const float* __restrict__ emb,
                                             const float* __restrict__ Wv,
                                             const float* __restrict__ Wsrc,
                                             const float* __restrict__ Wdst,
                                             float* __restrict__ ZG,
                                             float* __restrict__ QsG,
                                             float* __restrict__ QdG){
  __shared__ __align__(16) float Es[1152];
  const int n = blockIdx.x;
  const int t = threadIdx.x;
  {
    const float4* src = (const float4*)(emb + (size_t)n*1152);
    float4* dst = (float4*)Es;
    for(int idx=t; idx<288; idx+=128) dst[idx] = src[idx];
  }
  __syncthreads();
  const int l0 = (t>>6)*4;
  const int c0 = (t&63)*2;
  float z[5][2];
  #pragma unroll
  for(int il=0;il<5;il++){ z[il][0]=0.f; z[il][1]=0.f; }
  for(int c4=0;c4<32;c4++){
    float2 wv0 = *(const float2*)&Wv[(c4*4+0)*128 + c0];
    float2 wv1 = *(const float2*)&Wv[(c4*4+1)*128 + c0];
    float2 wv2 = *(const float2*)&Wv[(c4*4+2)*128 + c0];
    float2 wv3 = *(const float2*)&Wv[(c4*4+3)*128 + c0];
    #pragma unroll
    for(int il=0;il<5;il++){
      float4 x4 = *(const float4*)&Es[(l0+il)*128 + c4*4];
      z[il][0] += x4.x*wv0.x + x4.y*wv1.x + x4.z*wv2.x + x4.w*wv3.x;
      z[il][1] += x4.x*wv0.y + x4.y*wv1.y + x4.z*wv2.y + x4.w*wv3.y;
    }
  }
  #pragma unroll
  for(int il=0;il<5;il++){
    float2 o; o.x = z[il][0]; o.y = z[il][1];
    *(float2*)&ZG[(size_t)n*1152 + (l0+il)*128 + c0] = o;
  }
  {
    const float* W = (t < 64) ? Wsrc : Wdst;
    const int col = t & 63;
    float q = 0.f;
    for(int c=0;c<128;c++) q += Es[c] * W[c*64 + col];
    if(t < 64) QsG[n*64 + col] = q;
    else       QdG[n*64 + col] = q;
  }
}

// ---------------- K2: edge kernel — 2 nodes per 256-thread block ----------------
// Per-node pool (E_NPF floats). Within a node, 2 waves; wave w2 owns edges 8*w2..8*w2+7
// for P4/P5/P6; lane owns column pair (2*u2, 2*u2+1).
#define E_HD   0     /* 2048: hid rows e*128 (P4->P5, own-wave); aliases QS/QD/LG/SX */
#define E_QS   0     /* 1024, P1->P2 */
#define E_QD   1024  /* 64 */
#define E_LG   1088  /* 128 */
#define E_SX   1216  /* 16 */
#define E_EH   2048  /* 2048: eh rows e*128 (P5->P6, own-wave) */
#define E_RBW  4096  /* 256 */
#define E_AT   4352  /* 128 */
#define E_KI   4480  /* 16 ints */
#define E_KD   4496
#define E_LEN  4512
#define E_VL   4528
#define E_W0   4544
#define E_NPF  4608
__global__ __launch_bounds__(256) void k_edge(
    const float* __restrict__ coord,
    const float* __restrict__ We1, const float* __restrict__ be1,
    const float* __restrict__ We2, const float* __restrict__ be2,
    const float* __restrict__ wa,
    const float* __restrict__ Qs, const float* __restrict__ Qd,
    const float* __restrict__ Z,
    float* __restrict__ out){
  __shared__ __align__(16) float S[2*E_NPF];
  int* Si = (int*)S;
  const int t = threadIdx.x;
  const int h = t >> 7;
  const int u = t & 127;
  const int n = blockIdx.x*2 + h;
  const int base = n & ~(NPB - 1);
  const int self = n - base;
  const int NP = h * E_NPF;
  float* aggG = out + 12288;

  // ---- P0: stage coords once; waves 0 & 2 do the two KNNs ----
  for(int idx = t; idx < 3072; idx += 256) S[idx] = coord[base*3 + idx];
  __syncthreads();
  const float cx = S[self*3+0];
  const float cy = S[self*3+1];
  const float cz = S[self*3+2];
  if((t & 64) == 0){
    int lane = t & 63;
    float d2a[16]; int ida[16];
    for(int q=0;q<16;q++){
      int j = lane + q*64;
      float dx = __fsub_rn(S[j*3+0], cx);
      float dy = __fsub_rn(S[j*3+1], cy);
      float dz = __fsub_rn(S[j*3+2], cz);
      float d2 = __fadd_rn(__fadd_rn(__fmul_rn(dx,dx), __fmul_rn(dy,dy)), __fmul_rn(dz,dz));
      if(j == self) d2 = 3e38f;
      d2a[q] = d2; ida[q] = j;
    }
    for(int r=0;r<16;r++){
      float bd = d2a[0]; int bi = ida[0];
      for(int q=1;q<16;q++){
        bool bet = (d2a[q] < bd) || (d2a[q] == bd && ida[q] < bi);
        if(bet){ bd = d2a[q]; bi = ida[q]; }
      }
      for(int s=1;s<64;s<<=1){
        float od = __shfl_xor(bd, s, 64);
        int   oi = __shfl_xor(bi, s, 64);
        bool bet = (od < bd) || (od == bd && oi < bi);
        if(bet){ bd = od; bi = oi; }
      }
      if(lane == 0){ Si[NP + E_KI + r] = bi; S[NP + E_KD + r] = bd; }
      for(int q=0;q<16;q++) if(ida[q] == bi) d2a[q] = 3e38f;
    }
  }
  __syncthreads();

  // ---- P1: len/valid/window (u<16) + stage Qs[src] + Qd[n] ----
  if(u < 16){
    float len = __fsqrt_rn(S[NP + E_KD + u]);
    S[NP + E_LEN + u] = len;
    S[NP + E_VL + u]  = (len <= 3.0f) ? 1.0f : 0.0f;
    int i0 = (int)(len * (127.0f/3.0f) + 0.5f);
    int w0 = i0 - 7;
    w0 = w0 < 0 ? 0 : (w0 > 112 ? 112 : w0);
    Si[NP + E_W0 + u] = w0;
  }
  for(int idx = u; idx < 1024; idx += 128){
    int e = idx >> 6, ha = idx & 63;
    int src = base + Si[NP + E_KI + e];
    S[NP + E_QS + idx] = Qs[src*64 + ha];
  }
  if(u < 64) S[NP + E_QD + u] = Qd[n*64 + u];
  __syncthreads();

  // ---- P2: logits + windowed rbf ----
  {
    int e = u >> 3, hh = u & 7;
    float s = 0.f;
    #pragma unroll
    for(int a=0;a<8;a++){
      float q = S[NP + E_QD + hh*8 + a] + S[NP + E_QS + e*64 + hh*8 + a];
      s += siluf(q) * wa[hh*8 + a];
    }
    S[NP + E_LG + u] = (S[NP + E_VL + e] > 0.5f) ? s : -1e9f;

    const float step = 3.0f/127.0f;
    const float sigma = 3.0f/128.0f;
    for(int idx = u; idx < 256; idx += 128){
      int e2 = idx >> 4, w = idx & 15;
      int bin = Si[NP + E_W0 + e2] + w;
      float d = (S[NP + E_LEN + e2] - step*(float)bin) / sigma;
      S[NP + E_RBW + idx] = expf(-0.5f*d*d);
    }
  }
  __syncthreads();

  // ---- P3: softmax per head over 16 edges ----
  if(u < 8){
    float m = -3e38f;
    for(int r=0;r<16;r++) m = fmaxf(m, S[NP + E_LG + r*8 + u]);
    S[NP + E_SX + u] = m;
  }
  __syncthreads();
  {
    float ex = expf(S[NP + E_LG + u] - S[NP + E_SX + (u & 7)]);
    __syncthreads();
    S[NP + E_LG + u] = ex;
    __syncthreads();
    if(u < 8){
      float d = 0.f;
      for(int r=0;r<16;r++) d += S[NP + E_LG + r*8 + u];
      S[NP + E_SX + 8 + u] = d;
    }
    __syncthreads();
    S[NP + E_AT + u] = ex / (S[NP + E_SX + 8 + (u & 7)] + 1e-9f);
  }
  __syncthreads();

  // ---- P4: hid = silu(rbf @ We1 + b1), 16-bin window, 8 edges per wave ----
  const int w2 = (t >> 6) & 1;       // wave within node
  const int u2 = t & 63;
  const int c0 = u2*2;
  {
    float a4[8][2]; int b0[8];
    #pragma unroll
    for(int k=0;k<8;k++){ a4[k][0]=0.f; a4[k][1]=0.f; b0[k] = Si[NP + E_W0 + 8*w2 + k]; }
    for(int wi=0; wi<16; wi++){
      #pragma unroll
      for(int k=0;k<8;k++){
        float rb = S[NP + E_RBW + (8*w2+k)*16 + wi];
        float2 we = *(const float2*)&We1[(b0[k] + wi)*128 + c0];
        a4[k][0] = fmaf(rb, we.x, a4[k][0]);
        a4[k][1] = fmaf(rb, we.y, a4[k][1]);
      }
    }
    float2 be = *(const float2*)&be1[c0];
    #pragma unroll
    for(int k=0;k<8;k++){
      float2 o; o.x = siluf(a4[k][0] + be.x); o.y = siluf(a4[k][1] + be.y);
      *(float2*)&S[NP + E_HD + (8*w2+k)*128 + c0] = o;
    }
  }
  // no barrier: HD rows 8*w2.. are own-wave

  // ---- P5: eh = hid @ We2 + b2 (own 8 edges) ----
  {
    float a5[8][2];
    #pragma unroll
    for(int k=0;k<8;k++){ a5[k][0]=0.f; a5[k][1]=0.f; }
    for(int c4=0;c4<32;c4++){
      float2 w0 = *(const float2*)&We2[(c4*4+0)*128 + c0];
      float2 w1 = *(const float2*)&We2[(c4*4+1)*128 + c0];
      float2 w2v= *(const float2*)&We2[(c4*4+2)*128 + c0];
      float2 w3 = *(const float2*)&We2[(c4*4+3)*128 + c0];
      #pragma unroll
      for(int k=0;k<8;k++){
        float4 h4 = *(const float4*)&S[NP + E_HD + (8*w2+k)*128 + c4*4];
        a5[k][0] += h4.x*w0.x + h4.y*w1.x + h4.z*w2v.x + h4.w*w3.x;
        a5[k][1] += h4.x*w0.y + h4.y*w1.y + h4.z*w2v.y + h4.w*w3.y;
      }
    }
    float2 be = *(const float2*)&be2[c0];
    #pragma unroll
    for(int k=0;k<8;k++){
      float2 o; o.x = a5[k][0] + be.x; o.y = a5[k][1] + be.y;
      *(float2*)&S[NP + E_EH + (8*w2+k)*128 + c0] = o;
    }
  }
  __syncthreads();   // HD fully dead after this (needed before partial scratch reuse)

  // ---- P6: agg partials over own 8 edges; cross-wave add; store ----
  {
    float ag[9][2];
    #pragma unroll
    for(int l=0;l<9;l++){ ag[l][0]=0.f; ag[l][1]=0.f; }
    #pragma unroll
    for(int k=0;k<8;k++){
      int e = 8*w2 + k;
      const float* zp = &Z[(size_t)(base + Si[NP + E_KI + e])*1152 + c0];
      float at = S[NP + E_AT + e*8 + (c0>>4)];
      float2 eh2 = *(const float2*)&S[NP + E_EH + e*128 + c0];
      float sc0 = eh2.x * at;
      float sc1 = eh2.y * at;
      #pragma unroll
      for(int l=0;l<9;l++){
        float2 z2 = *(const float2*)&zp[l*128];
        ag[l][0] = fmaf(z2.x, sc0, ag[l][0]);
        ag[l][1] = fmaf(z2.y, sc1, ag[l][1]);
      }
    }
    if(w2 == 0){
      #pragma unroll
      for(int l=0;l<9;l++){
        float2 o; o.x = ag[l][0]; o.y = ag[l][1];
        *(float2*)&S[NP + l*128 + c0] = o;   // partial in dead HD region
      }
    }
    __syncthreads();
    if(w2 == 1){
      #pragma unroll
      for(int l=0;l<9;l++){
        float2 p = *(const float2*)&S[NP + l*128 + c0];
        float2 o; o.x = ag[l][0] + p.x; o.y = ag[l][1] + p.y;
        *(float2*)&aggG[(size_t)n*1152 + l*128 + c0] = o;
      }
    }
  }
}

// ---------------- K3: batched FFN — 4 nodes per 256-thread block ----------------
// Wave rg owns node n0+rg end-to-end. Lane owns column pair (2*u2, 2*u2+1).
// All LDS is wave-private -> ZERO barriers. rms via in-wave shfl.
#define FW_ACT 0      /* per-wave: act then HL tile, 9 x 128 */
#define FW_HID 1152   /* per-wave: hid tile, 9 x 128 (one 128-col f-tile) */
#define FW_SZ  2304
__global__ __launch_bounds__(256) void k_ffn(
    const float* __restrict__ emb,
    const float* __restrict__ Wo,
    const float* __restrict__ g1, const float* __restrict__ g2,
    const float* __restrict__ Wg, const float* __restrict__ Wf1,
    const float* __restrict__ Wf2,
    const float* __restrict__ filmG,
    float* __restrict__ out){
  __shared__ __align__(16) float S[4*FW_SZ];
  const int t = threadIdx.x;
  const int rg = t >> 6;
  const int u2 = t & 63;
  const int c0 = u2*2;
  const int n = blockIdx.x*4 + rg;
  float* W_ = &S[rg*FW_SZ];
  float* aggG = out + 12288;

  // stage own node's agg rows (wave-private)
  {
    const float4* src = (const float4*)(aggG + (size_t)n*1152);
    float4* dst = (float4*)&W_[FW_ACT];
    for(int i=u2;i<288;i+=64) dst[i] = src[i];
  }

  // GEMM1: x = agg @ Wo
  float x[9][2];
  #pragma unroll
  for(int l=0;l<9;l++){ x[l][0]=0.f; x[l][1]=0.f; }
  for(int c4=0;c4<32;c4++){
    float2 w0 = *(const float2*)&Wo[(c4*4+0)*128 + c0];
    float2 w1 = *(const float2*)&Wo[(c4*4+1)*128 + c0];
    float2 w2 = *(const float2*)&Wo[(c4*4+2)*128 + c0];
    float2 w3 = *(const float2*)&Wo[(c4*4+3)*128 + c0];
    #pragma unroll
    for(int l=0;l<9;l++){
      float4 a4 = *(const float4*)&W_[FW_ACT + l*128 + c4*4];
      x[l][0] += a4.x*w0.x + a4.y*w1.x + a4.z*w2.x + a4.w*w3.x;
      x[l][1] += a4.x*w0.y + a4.y*w1.y + a4.z*w2.y + a4.w*w3.y;
    }
  }

  // += emb; rms (in-wave shfl); HL -> overwrite act region
  float g2a = g2[c0], g2b = g2[c0+1];
  #pragma unroll
  for(int l=0;l<9;l++){
    float2 e2 = *(const float2*)&emb[(size_t)n*1152 + l*128 + c0];
    x[l][0] += e2.x; x[l][1] += e2.y;
    float sq = x[l][0]*x[l][0] + x[l][1]*x[l][1];
    #pragma unroll
    for(int s=1;s<64;s<<=1) sq += __shfl_xor(sq, s, 64);
    float ss = sqrtf(sq/128.f + 1e-6f);
    float2 o; o.x = x[l][0]/ss*g2a; o.y = x[l][1]/ss*g2b;
    *(float2*)&W_[FW_ACT + l*128 + c0] = o;
  }

  // GEMM2: both 128-col f-tiles at once: ha[ft][l][2], gate ga[ft][2]
  float ha[2][9][2]; float ga[2][2];
  #pragma unroll
  for(int ft=0;ft<2;ft++){
    ga[ft][0]=0.f; ga[ft][1]=0.f;
    #pragma unroll
    for(int l=0;l<9;l++){ ha[ft][l][0]=0.f; ha[ft][l][1]=0.f; }
  }
  for(int c4=0;c4<32;c4++){
    float2 wf[2][4], wg_[2][4];
    #pragma unroll
    for(int ft=0;ft<2;ft++)
      #pragma unroll
      for(int i=0;i<4;i++){
        wf[ft][i]  = *(const float2*)&Wf1[(c4*4+i)*256 + ft*128 + c0];
        wg_[ft][i] = *(const float2*)&Wg [(c4*4+i)*256 + ft*128 + c0];
      }
    float4 h0 = *(const float4*)&W_[FW_ACT + 0*128 + c4*4];
    #pragma unroll
    for(int ft=0;ft<2;ft++){
      ga[ft][0] += h0.x*wg_[ft][0].x + h0.y*wg_[ft][1].x + h0.z*wg_[ft][2].x + h0.w*wg_[ft][3].x;
      ga[ft][1] += h0.x*wg_[ft][0].y + h0.y*wg_[ft][1].y + h0.z*wg_[ft][2].y + h0.w*wg_[ft][3].y;
      ha[ft][0][0] += h0.x*wf[ft][0].x + h0.y*wf[ft][1].x + h0.z*wf[ft][2].x + h0.w*wf[ft][3].x;
      ha[ft][0][1] += h0.x*wf[ft][0].y + h0.y*wf[ft][1].y + h0.z*wf[ft][2].y + h0.w*wf[ft][3].y;
    }
    #pragma unroll
    for(int l=1;l<9;l++){
      float4 h4 = *(const float4*)&W_[FW_ACT + l*128 + c4*4];
      #pragma unroll
      for(int ft=0;ft<2;ft++){
        ha[ft][l][0] += h4.x*wf[ft][0].x + h4.y*wf[ft][1].x + h4.z*wf[ft][2].x + h4.w*wf[ft][3].x;
        ha[ft][l][1] += h4.x*wf[ft][0].y + h4.y*wf[ft][1].y + h4.z*wf[ft][2].y + h4.w*wf[ft][3].y;
      }
    }
  }

  // per f-tile: write hid (own-wave), GEMM3: x += hid @ Wf2[tile]
  #pragma unroll
  for(int ft=0;ft<2;ft++){
    float gx = siluf(ga[ft][0]), gy = siluf(ga[ft][1]);
    #pragma unroll
    for(int l=0;l<9;l++){
      float2 o; o.x = ha[ft][l][0]*gx; o.y = ha[ft][l][1]*gy;
      *(float2*)&W_[FW_HID + l*128 + c0] = o;
    }
    for(int f4=0;f4<32;f4++){
      float2 w0 = *(const float2*)&Wf2[(ft*128 + f4*4+0)*128 + c0];
      float2 w1 = *(const float2*)&Wf2[(ft*128 + f4*4+1)*128 + c0];
      float2 w2 = *(const float2*)&Wf2[(ft*128 + f4*4+2)*128 + c0];
      float2 w3 = *(const float2*)&Wf2[(ft*128 + f4*4+3)*128 + c0];
      #pragma unroll
      for(int l=0;l<9;l++){
        float4 h4 = *(const float4*)&W_[FW_HID + l*128 + f4*4];
        x[l][0] += h4.x*w0.x + h4.y*w1.x + h4.z*w2.x + h4.w*w3.x;
        x[l][1] += h4.x*w0.y + h4.y*w1.y + h4.z*w2.y + h4.w*w3.y;
      }
    }
  }

  // final rms (in-wave) + film + store
  {
    float g1a = g1[c0], g1b = g1[c0+1];
    int b = n >> 10;
    #pragma unroll
    for(int l=0;l<9;l++){
      float sq = x[l][0]*x[l][0] + x[l][1]*x[l][1];
      #pragma unroll
      for(int s=1;s<64;s<<=1) sq += __shfl_xor(sq, s, 64);
      float ss = sqrtf(sq/128.f + 1e-6f);
      float2 fw = *(const float2*)&filmG[b*2304 + l*128 + c0];
      float2 fb = *(const float2*)&filmG[b*2304 + 1152 + l*128 + c0];
      float2 o;
      o.x = x[l][0]/ss*g1a*fw.x + fb.x;
      o.y = x[l][1]/ss*g1b*fw.y + fb.y;
      *(float2*)&out[12288 + (size_t)n*1152 + l*128 + c0] = o;
    }
  }
}

// ---------- K4: coords (exact f32 copy) + batch (= n>>10, f32) ----------
__global__ __launch_bounds__(256) void k_copy(const float* __restrict__ coord,
                                              float* __restrict__ out){
  int i = blockIdx.x*256 + threadIdx.x;
  if(i < 12288) out[i] = coord[i];
  int n = i - 12288;
  if(n >= 0 && n < 4096) out[12288 + 4718592 + n] = (float)(n >> 10);
}

extern "C" void kernel_launch(void* const* d_in, const int* in_sizes, int n_in,
                              void* d_out, int out_size, void* d_ws, size_t ws_size,
                              hipStream_t stream) {
  const float* coord = (const float*)d_in[0];
  const float* emb   = (const float*)d_in[1];
  const float* cond  = (const float*)d_in[3];
  const float* We1   = (const float*)d_in[4];
  const float* be1   = (const float*)d_in[5];
  const float* We2   = (const float*)d_in[6];
  const float* be2   = (const float*)d_in[7];
  const float* Wsrc  = (const float*)d_in[8];
  const float* Wdst  = (const float*)d_in[9];
  const float* wa    = (const float*)d_in[10];
  const float* Wv    = (const float*)d_in[11];
  const float* Wo    = (const float*)d_in[12];
  const float* g1    = (const float*)d_in[13];
  const float* g2    = (const float*)d_in[14];
  const float* Wg    = (const float*)d_in[15];
  const float* Wf1   = (const float*)d_in[16];
  const float* Wf2   = (const float*)d_in[17];
  const float* Wfilm = (const float*)d_in[18];
  const float* bfilm = (const float*)d_in[19];

  float* outf  = (float*)d_out;
  // workspace (floats): filmG 9216 | QsG 262144 | QdG 262144 | ZG 4718592 (~21 MB)
  // agg lives in the out buffer (out+12288), consumed in-place by k_ffn.
  float* filmG = (float*)d_ws;
  float* QsG   = filmG + 9216;
  float* QdG   = QsG + 262144;
  float* ZG    = QdG + 262144;

  k_film<<<dim3(9,4), 256, 0, stream>>>(cond, Wfilm, bfilm, filmG);
  k_pre<<<NNODE, 128, 0, stream>>>(emb, Wv, Wsrc, Wdst, ZG, QsG, QdG);
  k_edge<<<NNODE/2, 256, 0, stream>>>(coord, We1, be1, We2, be2, wa,
                                      QsG, QdG, ZG, outf);
  k_ffn<<<NNODE/4, 256, 0, stream>>>(emb, Wo, g1, g2, Wg, Wf1, Wf2,
                                     filmG, outf);
  k_copy<<<64, 256, 0, stream>>>(coord, outf);
}

// Round 5
// 410.650 us; speedup vs baseline: 3.5210x; 1.0779x over previous
//
#include <hip/hip_runtime.h>

#define NNODE 4096
#define NPB   1024

__device__ __forceinline__ float siluf(float x){ return x / (1.0f + expf(-x)); }

// ---------- K0: film = mish(cond) @ Wfilm + bfilm -> d_ws (4 x 2304 f32) ----------
__global__ __launch_bounds__(256) void k_film(const float* __restrict__ cond,
                                              const float* __restrict__ Wfilm,
                                              const float* __restrict__ bfilm,
                                              float* __restrict__ filmG){
  __shared__ float mL[256];
  int b = blockIdx.y;
  int t = threadIdx.x;
  int j = blockIdx.x*256 + t;
  float x = cond[b*256 + t];
  float sp = fmaxf(x, 0.f) + log1pf(expf(-fabsf(x)));
  mL[t] = x * tanhf(sp);
  __syncthreads();
  if(j >= 2304) return;
  float acc = bfilm[j];
  for(int i=0;i<256;i++) acc += mL[i] * Wfilm[i*2304 + j];
  filmG[b*2304 + j] = acc;
}

// ---------- K1: per-node precompute, wave-per-node, no LDS, no barriers ----------
// Z  = emb @ Wv  (N x 9 x 128); Qs = emb[:,0] @ Wsrc (N x 64); Qd = emb[:,0] @ Wdst
__global__ __launch_bounds__(256) void k_pre(const float* __restrict__ emb,
                                             const float* __restrict__ Wv,
                                             const float* __restrict__ Wsrc,
                                             const float* __restrict__ Wdst,
                                             float* __restrict__ ZG,
                                             float* __restrict__ QsG,
                                             float* __restrict__ QdG){
  const int t = threadIdx.x;
  const int rg = __builtin_amdgcn_readfirstlane(t >> 6);
  const int lane = t & 63;
  const int c0 = lane*2;
  const int n = blockIdx.x*4 + rg;
  const float* en = emb + (size_t)n*1152;   // wave-uniform base

  float z[9][2];
  #pragma unroll
  for(int l=0;l<9;l++){ z[l][0]=0.f; z[l][1]=0.f; }
  for(int c4=0;c4<32;c4++){
    float2 wv0 = *(const float2*)&Wv[(c4*4+0)*128 + c0];
    float2 wv1 = *(const float2*)&Wv[(c4*4+1)*128 + c0];
    float2 wv2 = *(const float2*)&Wv[(c4*4+2)*128 + c0];
    float2 wv3 = *(const float2*)&Wv[(c4*4+3)*128 + c0];
    #pragma unroll
    for(int l=0;l<9;l++){
      float4 x4 = *(const float4*)&en[l*128 + c4*4];   // uniform broadcast
      z[l][0] += x4.x*wv0.x + x4.y*wv1.x + x4.z*wv2.x + x4.w*wv3.x;
      z[l][1] += x4.x*wv0.y + x4.y*wv1.y + x4.z*wv2.y + x4.w*wv3.y;
    }
  }
  #pragma unroll
  for(int l=0;l<9;l++){
    float2 o; o.x=z[l][0]; o.y=z[l][1];
    *(float2*)&ZG[(size_t)n*1152 + l*128 + c0] = o;
  }
  float qs = 0.f, qd = 0.f;
  for(int c=0;c<128;c++){
    float ec = en[c];                      // uniform scalar
    qs = fmaf(ec, Wsrc[c*64 + lane], qs);
    qd = fmaf(ec, Wdst[c*64 + lane], qd);
  }
  QsG[n*64 + lane] = qs;
  QdG[n*64 + lane] = qd;
}

// ---------------- K2: edge kernel — wave-per-node, 2 nodes / 128-thread block ----
// Per-node LDS pool (E2_NPF floats), all wave-private after barrier 1:
//   HD 0..2048 | RB 2048..2304 | AT 2304..2432 | KI 2432 | LEN 2448 | VL 2464 | W0 2480
#define E2_HD   0
#define E2_RB   2048
#define E2_AT   2304
#define E2_KI   2432
#define E2_LEN  2448
#define E2_VL   2464
#define E2_W0   2480
#define E2_NPF  2560
__global__ __launch_bounds__(128) void k_edge(
    const float* __restrict__ coord,
    const float* __restrict__ We1, const float* __restrict__ be1,
    const float* __restrict__ We2, const float* __restrict__ be2,
    const float* __restrict__ wa,
    const float* __restrict__ Qs, const float* __restrict__ Qd,
    const float* __restrict__ Z,
    float* __restrict__ out){
  __shared__ __align__(16) float S[2*E2_NPF];
  int* Si = (int*)S;
  const int t = threadIdx.x;
  const int w = __builtin_amdgcn_readfirstlane(t >> 6);
  const int lane = t & 63;
  const int n = blockIdx.x*2 + w;
  const int base = n & ~(NPB - 1);
  const int self = n - base;
  const int NP = w * E2_NPF;
  const int c0 = lane*2;
  const int myh = lane >> 3;
  float* aggG = out + 12288;

  // ---- KNN: every wave does its own node, coords straight from L1/L2 ----
  {
    const float* cb = coord + (size_t)base*3;
    const float cx = cb[self*3+0];
    const float cy = cb[self*3+1];
    const float cz = cb[self*3+2];
    float d2a[16]; int ida[16];
    #pragma unroll
    for(int q=0;q<16;q++){
      int j = lane + q*64;
      float dx = __fsub_rn(cb[j*3+0], cx);
      float dy = __fsub_rn(cb[j*3+1], cy);
      float dz = __fsub_rn(cb[j*3+2], cz);
      float d2 = __fadd_rn(__fadd_rn(__fmul_rn(dx,dx), __fmul_rn(dy,dy)), __fmul_rn(dz,dz));
      if(j == self) d2 = 3e38f;
      d2a[q] = d2; ida[q] = j;
    }
    for(int r=0;r<16;r++){
      float bd = d2a[0]; int bi = ida[0];
      #pragma unroll
      for(int q=1;q<16;q++){
        bool bet = (d2a[q] < bd) || (d2a[q] == bd && ida[q] < bi);
        if(bet){ bd = d2a[q]; bi = ida[q]; }
      }
      for(int s=1;s<64;s<<=1){
        float od = __shfl_xor(bd, s, 64);
        int   oi = __shfl_xor(bi, s, 64);
        bool bet = (od < bd) || (od == bd && oi < bi);
        if(bet){ bd = od; bi = oi; }
      }
      if(lane == 0){
        Si[NP + E2_KI + r] = bi;
        float len = __fsqrt_rn(bd);
        S[NP + E2_LEN + r] = len;
        S[NP + E2_VL + r]  = (len <= 3.0f) ? 1.0f : 0.0f;
        int i0 = (int)(len * (127.0f/3.0f) + 0.5f);
        int w0 = i0 - 7;
        w0 = w0 < 0 ? 0 : (w0 > 112 ? 112 : w0);
        Si[NP + E2_W0 + r] = w0;
      }
      #pragma unroll
      for(int q=0;q<16;q++) if(ida[q] == bi) d2a[q] = 3e38f;
    }
  }
  __syncthreads();

  // ---- logits (2 slots per lane) + in-wave softmax + windowed rbf ----
  {
    const int e0 = lane >> 3, hh = lane & 7;
    float4 qda = *(const float4*)&Qd[(size_t)n*64 + hh*8];
    float4 qdb = *(const float4*)&Qd[(size_t)n*64 + hh*8 + 4];
    float4 waa = *(const float4*)&wa[hh*8];
    float4 wab = *(const float4*)&wa[hh*8 + 4];
    float lg[2];
    #pragma unroll
    for(int s=0;s<2;s++){
      int e = e0 + s*8;
      int src = base + Si[NP + E2_KI + e];
      float4 qa = *(const float4*)&Qs[(size_t)src*64 + hh*8];
      float4 qb = *(const float4*)&Qs[(size_t)src*64 + hh*8 + 4];
      float sv = siluf(qda.x+qa.x)*waa.x + siluf(qda.y+qa.y)*waa.y
               + siluf(qda.z+qa.z)*waa.z + siluf(qda.w+qa.w)*waa.w
               + siluf(qdb.x+qb.x)*wab.x + siluf(qdb.y+qb.y)*wab.y
               + siluf(qdb.z+qb.z)*wab.z + siluf(qdb.w+qb.w)*wab.w;
      lg[s] = (S[NP + E2_VL + e] > 0.5f) ? sv : -1e9f;
    }
    float m = fmaxf(lg[0], lg[1]);
    m = fmaxf(m, __shfl_xor(m, 8, 64));
    m = fmaxf(m, __shfl_xor(m, 16, 64));
    m = fmaxf(m, __shfl_xor(m, 32, 64));
    float ex0 = expf(lg[0] - m), ex1 = expf(lg[1] - m);
    float den = ex0 + ex1;
    den += __shfl_xor(den, 8, 64);
    den += __shfl_xor(den, 16, 64);
    den += __shfl_xor(den, 32, 64);
    float inv = 1.0f/(den + 1e-9f);
    S[NP + E2_AT + lane]      = ex0*inv;   // slot (e0, hh)   at e*8+h == lane
    S[NP + E2_AT + 64 + lane] = ex1*inv;   // slot (e0+8, hh) at e*8+h == lane+64

    const float step = 3.0f/127.0f;
    const float sigma = 3.0f/128.0f;
    #pragma unroll
    for(int k=0;k<4;k++){
      int idx = lane + k*64;
      int e = idx >> 4, wi = idx & 15;
      float len = S[NP + E2_LEN + e];
      int bin = Si[NP + E2_W0 + e] + wi;
      float d = (len - step*(float)bin) / sigma;
      S[NP + E2_RB + idx] = expf(-0.5f*d*d);
    }
  }
  __syncthreads();

  // ---- P4: hid = silu(rbf @ We1 + b1), all 16 edges, lane owns col pair ----
  {
    float a4[16][2]; int b0e[16];
    #pragma unroll
    for(int e=0;e<16;e++){ a4[e][0]=0.f; a4[e][1]=0.f; b0e[e] = Si[NP + E2_W0 + e]; }
    for(int wi=0; wi<16; wi++){
      #pragma unroll
      for(int e=0;e<16;e++){
        float rb = S[NP + E2_RB + e*16 + wi];
        float2 we = *(const float2*)&We1[(size_t)(b0e[e] + wi)*128 + c0];
        a4[e][0] = fmaf(rb, we.x, a4[e][0]);
        a4[e][1] = fmaf(rb, we.y, a4[e][1]);
      }
    }
    float2 b1v = *(const float2*)&be1[c0];
    #pragma unroll
    for(int e=0;e<16;e++){
      float2 o; o.x = siluf(a4[e][0] + b1v.x); o.y = siluf(a4[e][1] + b1v.y);
      *(float2*)&S[NP + E2_HD + e*128 + c0] = o;
    }
  }
  __syncthreads();

  // ---- P5: eh = hid @ We2 + b2 — result stays in registers (lane-local cols) ----
  float a5[16][2];
  #pragma unroll
  for(int e=0;e<16;e++){ a5[e][0]=0.f; a5[e][1]=0.f; }
  for(int c4=0;c4<32;c4++){
    float2 w0 = *(const float2*)&We2[(c4*4+0)*128 + c0];
    float2 w1 = *(const float2*)&We2[(c4*4+1)*128 + c0];
    float2 w2 = *(const float2*)&We2[(c4*4+2)*128 + c0];
    float2 w3 = *(const float2*)&We2[(c4*4+3)*128 + c0];
    #pragma unroll
    for(int e=0;e<16;e++){
      float4 h4 = *(const float4*)&S[NP + E2_HD + e*128 + c4*4];
      a5[e][0] += h4.x*w0.x + h4.y*w1.x + h4.z*w2.x + h4.w*w3.x;
      a5[e][1] += h4.x*w0.y + h4.y*w1.y + h4.z*w2.y + h4.w*w3.y;
    }
  }

  // ---- P6: agg[l,c] = sum_e Z[src_e,l,c] * eh[e,c] * attn[e, c>>4] ----
  {
    float2 b2v = *(const float2*)&be2[c0];
    float ag[9][2];
    #pragma unroll
    for(int l=0;l<9;l++){ ag[l][0]=0.f; ag[l][1]=0.f; }
    #pragma unroll
    for(int e=0;e<16;e++){
      int src = base + Si[NP + E2_KI + e];
      const float* zp = &Z[(size_t)src*1152 + c0];
      float at = S[NP + E2_AT + e*8 + myh];
      float sc0 = (a5[e][0] + b2v.x) * at;
      float sc1 = (a5[e][1] + b2v.y) * at;
      #pragma unroll
      for(int l=0;l<9;l++){
        float2 z2 = *(const float2*)&zp[l*128];
        ag[l][0] = fmaf(z2.x, sc0, ag[l][0]);
        ag[l][1] = fmaf(z2.y, sc1, ag[l][1]);
      }
    }
    #pragma unroll
    for(int l=0;l<9;l++){
      float2 o; o.x = ag[l][0]; o.y = ag[l][1];
      *(float2*)&aggG[(size_t)n*1152 + l*128 + c0] = o;
    }
  }
}

// ---------------- K3: batched FFN — wave-per-node, 4 nodes / 256-thread block ----
// GEMM1 reads agg straight from global (wave-uniform broadcast) — no LDS staging.
#define FW_ACT 0      /* per-wave: HL tile, 9 x 128 */
#define FW_HID 1152   /* per-wave: hid tile, 9 x 128 (one 128-col f-tile) */
#define FW_SZ  2304
__global__ __launch_bounds__(256) void k_ffn(
    const float* __restrict__ emb,
    const float* __restrict__ Wo,
    const float* __restrict__ g1, const float* __restrict__ g2,
    const float* __restrict__ Wg, const float* __restrict__ Wf1,
    const float* __restrict__ Wf2,
    const float* __restrict__ filmG,
    float* __restrict__ out){
  __shared__ __align__(16) float S[4*FW_SZ];
  const int t = threadIdx.x;
  const int rg = __builtin_amdgcn_readfirstlane(t >> 6);
  const int u2 = t & 63;
  const int c0 = u2*2;
  const int n = blockIdx.x*4 + rg;
  float* W_ = &S[rg*FW_SZ];
  float* aggG = out + 12288;
  const float* agp = aggG + (size_t)n*1152;   // wave-uniform base

  // GEMM1: x = agg @ Wo (agg read as uniform broadcast from global)
  float x[9][2];
  #pragma unroll
  for(int l=0;l<9;l++){ x[l][0]=0.f; x[l][1]=0.f; }
  for(int c4=0;c4<32;c4++){
    float2 w0 = *(const float2*)&Wo[(c4*4+0)*128 + c0];
    float2 w1 = *(const float2*)&Wo[(c4*4+1)*128 + c0];
    float2 w2 = *(const float2*)&Wo[(c4*4+2)*128 + c0];
    float2 w3 = *(const float2*)&Wo[(c4*4+3)*128 + c0];
    #pragma unroll
    for(int l=0;l<9;l++){
      float4 a4 = *(const float4*)&agp[l*128 + c4*4];
      x[l][0] += a4.x*w0.x + a4.y*w1.x + a4.z*w2.x + a4.w*w3.x;
      x[l][1] += a4.x*w0.y + a4.y*w1.y + a4.z*w2.y + a4.w*w3.y;
    }
  }

  // += emb; rms (in-wave shfl); HL -> LDS
  float g2a = g2[c0], g2b = g2[c0+1];
  #pragma unroll
  for(int l=0;l<9;l++){
    float2 e2 = *(const float2*)&emb[(size_t)n*1152 + l*128 + c0];
    x[l][0] += e2.x; x[l][1] += e2.y;
    float sq = x[l][0]*x[l][0] + x[l][1]*x[l][1];
    #pragma unroll
    for(int s=1;s<64;s<<=1) sq += __shfl_xor(sq, s, 64);
    float ss = sqrtf(sq/128.f + 1e-6f);
    float2 o; o.x = x[l][0]/ss*g2a; o.y = x[l][1]/ss*g2b;
    *(float2*)&W_[FW_ACT + l*128 + c0] = o;
  }

  // GEMM2: both 128-col f-tiles at once: ha[ft][l][2], gate ga[ft][2]
  float ha[2][9][2]; float ga[2][2];
  #pragma unroll
  for(int ft=0;ft<2;ft++){
    ga[ft][0]=0.f; ga[ft][1]=0.f;
    #pragma unroll
    for(int l=0;l<9;l++){ ha[ft][l][0]=0.f; ha[ft][l][1]=0.f; }
  }
  for(int c4=0;c4<32;c4++){
    float2 wf[2][4], wg_[2][4];
    #pragma unroll
    for(int ft=0;ft<2;ft++)
      #pragma unroll
      for(int i=0;i<4;i++){
        wf[ft][i]  = *(const float2*)&Wf1[(c4*4+i)*256 + ft*128 + c0];
        wg_[ft][i] = *(const float2*)&Wg [(c4*4+i)*256 + ft*128 + c0];
      }
    float4 h0 = *(const float4*)&W_[FW_ACT + 0*128 + c4*4];
    #pragma unroll
    for(int ft=0;ft<2;ft++){
      ga[ft][0] += h0.x*wg_[ft][0].x + h0.y*wg_[ft][1].x + h0.z*wg_[ft][2].x + h0.w*wg_[ft][3].x;
      ga[ft][1] += h0.x*wg_[ft][0].y + h0.y*wg_[ft][1].y + h0.z*wg_[ft][2].y + h0.w*wg_[ft][3].y;
      ha[ft][0][0] += h0.x*wf[ft][0].x + h0.y*wf[ft][1].x + h0.z*wf[ft][2].x + h0.w*wf[ft][3].x;
      ha[ft][0][1] += h0.x*wf[ft][0].y + h0.y*wf[ft][1].y + h0.z*wf[ft][2].y + h0.w*wf[ft][3].y;
    }
    #pragma unroll
    for(int l=1;l<9;l++){
      float4 h4 = *(const float4*)&W_[FW_ACT + l*128 + c4*4];
      #pragma unroll
      for(int ft=0;ft<2;ft++){
        ha[ft][l][0] += h4.x*wf[ft][0].x + h4.y*wf[ft][1].x + h4.z*wf[ft][2].x + h4.w*wf[ft][3].x;
        ha[ft][l][1] += h4.x*wf[ft][0].y + h4.y*wf[ft][1].y + h4.z*wf[ft][2].y + h4.w*wf[ft][3].y;
      }
    }
  }

  // per f-tile: write hid (own-wave), GEMM3: x += hid @ Wf2[tile]
  #pragma unroll
  for(int ft=0;ft<2;ft++){
    float gx = siluf(ga[ft][0]), gy = siluf(ga[ft][1]);
    #pragma unroll
    for(int l=0;l<9;l++){
      float2 o; o.x = ha[ft][l][0]*gx; o.y = ha[ft][l][1]*gy;
      *(float2*)&W_[FW_HID + l*128 + c0] = o;
    }
    for(int f4=0;f4<32;f4++){
      float2 w0 = *(const float2*)&Wf2[(ft*128 + f4*4+0)*128 + c0];
      float2 w1 = *(const float2*)&Wf2[(ft*128 + f4*4+1)*128 + c0];
      float2 w2 = *(const float2*)&Wf2[(ft*128 + f4*4+2)*128 + c0];
      float2 w3 = *(const float2*)&Wf2[(ft*128 + f4*4+3)*128 + c0];
      #pragma unroll
      for(int l=0;l<9;l++){
        float4 h4 = *(const float4*)&W_[FW_HID + l*128 + f4*4];
        x[l][0] += h4.x*w0.x + h4.y*w1.x + h4.z*w2.x + h4.w*w3.x;
        x[l][1] += h4.x*w0.y + h4.y*w1.y + h4.z*w2.y + h4.w*w3.y;
      }
    }
  }

  // final rms (in-wave) + film + store
  {
    float g1a = g1[c0], g1b = g1[c0+1];
    int b = n >> 10;
    #pragma unroll
    for(int l=0;l<9;l++){
      float sq = x[l][0]*x[l][0] + x[l][1]*x[l][1];
      #pragma unroll
      for(int s=1;s<64;s<<=1) sq += __shfl_xor(sq, s, 64);
      float ss = sqrtf(sq/128.f + 1e-6f);
      float2 fw = *(const float2*)&filmG[b*2304 + l*128 + c0];
      float2 fb = *(const float2*)&filmG[b*2304 + 1152 + l*128 + c0];
      float2 o;
      o.x = x[l][0]/ss*g1a*fw.x + fb.x;
      o.y = x[l][1]/ss*g1b*fw.y + fb.y;
      *(float2*)&out[12288 + (size_t)n*1152 + l*128 + c0] = o;
    }
  }
}

// ---------- K4: coords (exact f32 copy) + batch (= n>>10, f32) ----------
__global__ __launch_bounds__(256) void k_copy(const float* __restrict__ coord,
                                              float* __restrict__ out){
  int i = blockIdx.x*256 + threadIdx.x;
  if(i < 12288) out[i] = coord[i];
  int n = i - 12288;
  if(n >= 0 && n < 4096) out[12288 + 4718592 + n] = (float)(n >> 10);
}

extern "C" void kernel_launch(void* const* d_in, const int* in_sizes, int n_in,
                              void* d_out, int out_size, void* d_ws, size_t ws_size,
                              hipStream_t stream) {
  const float* coord = (const float*)d_in[0];
  const float* emb   = (const float*)d_in[1];
  const float* cond  = (const float*)d_in[3];
  const float* We1   = (const float*)d_in[4];
  const float* be1   = (const float*)d_in[5];
  const float* We2   = (const float*)d_in[6];
  const float* be2   = (const float*)d_in[7];
  const float* Wsrc  = (const float*)d_in[8];
  const float* Wdst  = (const float*)d_in[9];
  const float* wa    = (const float*)d_in[10];
  const float* Wv    = (const float*)d_in[11];
  const float* Wo    = (const float*)d_in[12];
  const float* g1    = (const float*)d_in[13];
  const float* g2    = (const float*)d_in[14];
  const float* Wg    = (const float*)d_in[15];
  const float* Wf1   = (const float*)d_in[16];
  const float* Wf2   = (const float*)d_in[17];
  const float* Wfilm = (const float*)d_in[18];
  const float* bfilm = (const float*)d_in[19];

  float* outf  = (float*)d_out;
  // workspace (floats): filmG 9216 | QsG 262144 | QdG 262144 | ZG 4718592 (~21 MB)
  // agg lives in the out buffer (out+12288), consumed in-place by k_ffn.
  float* filmG = (float*)d_ws;
  float* QsG   = filmG + 9216;
  float* QdG   = QsG + 262144;
  float* ZG    = QdG + 262144;

  k_film<<<dim3(9,4), 256, 0, stream>>>(cond, Wfilm, bfilm, filmG);
  k_pre<<<NNODE/4, 256, 0, stream>>>(emb, Wv, Wsrc, Wdst, ZG, QsG, QdG);
  k_edge<<<NNODE/2, 128, 0, stream>>>(coord, We1, be1, We2, be2, wa,
                                      QsG, QdG, ZG, outf);
  k_ffn<<<NNODE/4, 256, 0, stream>>>(emb, Wo, g1, g2, Wg, Wf1, Wf2,
                                     filmG, outf);
  k_copy<<<64, 256, 0, stream>>>(coord, outf);
}